// Round 1
// baseline (2546.834 us; speedup 1.0000x reference)
//
#include <hip/hip_runtime.h>
#include <hip/hip_bf16.h>
#include <math.h>

// Problem constants
constexpr int cB   = 4;
constexpr int cL   = 1024;
constexpr int cH   = 1024;
constexpr int cA   = 16;
constexpr int cM   = 128;
constexpr int cE   = 32;
constexpr int cR   = 992;
constexpr int cEMB = 768;
constexpr int cC   = 97;
constexpr int cN   = cB * cR;  // 3968

// ---------------------------------------------------------------------------
// Kernel 1: per-(b,e) logsumexp pooling of ent_lhs over mentions + counts
// grid (cE, cB), block 256
__global__ void ent_pool_k(const float* __restrict__ ent_lhs, const int* __restrict__ ids,
                           float* __restrict__ ent_emb, int* __restrict__ counts) {
    int e = blockIdx.x, b = blockIdx.y;
    __shared__ int sid[cM];
    int tid = threadIdx.x;
    if (tid < cM) sid[tid] = ids[b * cM + tid];
    __syncthreads();
    int cnt = 0;
    for (int m = 0; m < cM; m++) cnt += (sid[m] == e) ? 1 : 0;
    if (tid == 0) counts[b * cE + e] = cnt;
    for (int h = tid; h < cH; h += 256) {
        float mx = -1e30f;
        for (int m = 0; m < cM; m++)
            if (sid[m] == e) mx = fmaxf(mx, ent_lhs[(size_t)(b * cM + m) * cH + h]);
        float s = 0.f;
        for (int m = 0; m < cM; m++)
            if (sid[m] == e) s += __expf(ent_lhs[(size_t)(b * cM + m) * cH + h] - mx);
        ent_emb[(size_t)(b * cE + e) * cH + h] = (cnt > 0) ? (mx + __logf(s)) : 0.f;
    }
}

// ---------------------------------------------------------------------------
// Kernel 2: ent_attn[b][e][a][l] = sum_{m: ids==e} attn[b][a][m][l] / max(count,1)
// grid (cB*cA, cL/256), block 256. Per-thread E accumulators in LDS (stride 33
// so addr%32 == e -> all 32 banks hit, 2 lanes/bank = free).
__global__ void ent_attn_k(const float* __restrict__ attn, const int* __restrict__ ids,
                           const int* __restrict__ counts, float* __restrict__ ent_attn) {
    int ba = blockIdx.x;
    int b = ba / cA, a = ba % cA;
    int tid = threadIdx.x;
    int l = blockIdx.y * 256 + tid;
    __shared__ int sid[cM];
    __shared__ int scnt[cE];
    __shared__ float sacc[256 * 33];
    if (tid < cM) sid[tid] = ids[b * cM + tid];
    if (tid < cE) scnt[tid] = counts[b * cE + tid];
    float* acc = &sacc[tid * 33];
    for (int e2 = 0; e2 < cE; e2++) acc[e2] = 0.f;
    __syncthreads();
    const float* ap = attn + ((size_t)(b * cA + a) * cM) * cL + l;
    for (int m = 0; m < cM; m++) acc[sid[m]] += ap[(size_t)m * cL];
    for (int e2 = 0; e2 < cE; e2++) {
        // count==0 -> acc==0 -> output 0, matching the reference's where()
        ent_attn[((size_t)(b * cE + e2) * cA + a) * cL + l] =
            acc[e2] / (float)max(scnt[e2], 1);
    }
}

// ---------------------------------------------------------------------------
// Kernel 3: w[b][r][l] = mean_a ha*ta, normalized over l.  grid cN, block 256
__global__ void w_k(const float* __restrict__ ent_attn, const int* __restrict__ hts,
                    float* __restrict__ w) {
    int nr = blockIdx.x;          // nr = b*cR + r
    int b = nr / cR;
    int he = hts[nr * 2 + 0], te = hts[nr * 2 + 1];
    int tid = threadIdx.x;
    const float* ha = ent_attn + ((size_t)(b * cE + he) * cA) * cL;
    const float* ta = ent_attn + ((size_t)(b * cE + te) * cA) * cL;
    float v[4];
    float psum = 0.f;
    for (int i = 0; i < 4; i++) {
        int l = tid + i * 256;
        float s = 0.f;
        for (int a = 0; a < cA; a++) s += ha[(size_t)a * cL + l] * ta[(size_t)a * cL + l];
        s *= (1.0f / cA);
        v[i] = s;
        psum += s;
    }
    for (int off = 32; off > 0; off >>= 1) psum += __shfl_down(psum, off, 64);
    __shared__ float red[4];
    if ((tid & 63) == 0) red[tid >> 6] = psum;
    __syncthreads();
    float tot = red[0] + red[1] + red[2] + red[3];
    float inv = 1.0f / (tot + 1e-5f);
    for (int i = 0; i < 4; i++) w[(size_t)nr * cL + tid + i * 256] = v[i] * inv;
}

// ---------------------------------------------------------------------------
// Kernel 4: rel[b][r][h] = sum_l w[b][r][l] * seq[b][l][h]
// 64x64 tile, KT=16, 16x16 threads with 4x4 microtile. grid (16,16,cB)
__global__ void rel_gemm_k(const float* __restrict__ w, const float* __restrict__ seq,
                           float* __restrict__ rel) {
    int b = blockIdx.z;
    int r0 = blockIdx.x * 64, h0 = blockIdx.y * 64;
    int tid = threadIdx.x, tx = tid % 16, ty = tid / 16;
    __shared__ float As[64][17];
    __shared__ float Bs[16][68];
    float acc[4][4] = {};
    for (int kt = 0; kt < cL; kt += 16) {
        for (int i = 0; i < 4; i++) {
            int rr = ty + i * 16;
            int r = r0 + rr;
            As[rr][tx] = (r < cR) ? w[((size_t)b * cR + r) * cL + kt + tx] : 0.f;
        }
        for (int i = 0; i < 4; i++) {
            int hh = tx + i * 16;
            Bs[ty][hh] = seq[((size_t)b * cL + kt + ty) * cH + h0 + hh];
        }
        __syncthreads();
#pragma unroll
        for (int k = 0; k < 16; k++) {
            float av[4], bv[4];
            for (int i = 0; i < 4; i++) av[i] = As[ty + 16 * i][k];
            for (int j = 0; j < 4; j++) bv[j] = Bs[k][tx + 16 * j];
            for (int i = 0; i < 4; i++)
                for (int j = 0; j < 4; j++) acc[i][j] += av[i] * bv[j];
        }
        __syncthreads();
    }
    for (int i = 0; i < 4; i++) {
        int r = r0 + ty + 16 * i;
        if (r < cR)
            for (int j = 0; j < 4; j++)
                rel[((size_t)b * cR + r) * cH + h0 + tx + 16 * j] = acc[i][j];
    }
}

// ---------------------------------------------------------------------------
// Kernel 5: projection GEMM with gathered A: out[n][e] =
//   tanh( sum_{k<1024} ent_emb[b][ht[n][sel]][k]*W[k][e]
//       + sum_{k} rel[n][k]*W[1024+k][e] + bias[e] )
// M=3968 (62 tiles), N=768 (12 tiles), K=2048.
__global__ void proj_k(const float* __restrict__ ent_emb, const float* __restrict__ rel,
                       const int* __restrict__ hts, const float* __restrict__ W,
                       const float* __restrict__ bias, float* __restrict__ outp, int sel) {
    int n0 = blockIdx.x * 64, e0 = blockIdx.y * 64;
    int tid = threadIdx.x, tx = tid % 16, ty = tid / 16;
    __shared__ int sbase[64];
    if (tid < 64) {
        int n = n0 + tid;
        int b = n / cR;
        int ent = hts[n * 2 + sel];
        sbase[tid] = (b * cE + ent) * cH;
    }
    __shared__ float As[64][17];
    __shared__ float Bs[16][68];
    float acc[4][4] = {};
    __syncthreads();
    for (int kt = 0; kt < 2 * cH; kt += 16) {
        bool first = kt < cH;
        for (int i = 0; i < 4; i++) {
            int rr = ty + i * 16;
            int n = n0 + rr;
            As[rr][tx] = first ? ent_emb[(size_t)sbase[rr] + kt + tx]
                               : rel[(size_t)n * cH + kt - cH + tx];
        }
        for (int i = 0; i < 4; i++) {
            int ee = tx + i * 16;
            Bs[ty][ee] = W[(size_t)(kt + ty) * cEMB + e0 + ee];
        }
        __syncthreads();
#pragma unroll
        for (int k = 0; k < 16; k++) {
            float av[4], bv[4];
            for (int i = 0; i < 4; i++) av[i] = As[ty + 16 * i][k];
            for (int j = 0; j < 4; j++) bv[j] = Bs[k][tx + 16 * j];
            for (int i = 0; i < 4; i++)
                for (int j = 0; j < 4; j++) acc[i][j] += av[i] * bv[j];
        }
        __syncthreads();
    }
    for (int i = 0; i < 4; i++) {
        int n = n0 + ty + 16 * i;
        for (int j = 0; j < 4; j++) {
            int ee = e0 + tx + 16 * j;
            outp[(size_t)n * cEMB + ee] = tanhf(acc[i][j] + bias[ee]);
        }
    }
}

// ---------------------------------------------------------------------------
// Kernel 6a: out init with bias
__global__ void out_init_k(const float* __restrict__ bil_b, float* __restrict__ out) {
    int idx = blockIdx.x * 256 + threadIdx.x;
    if (idx < cN * cC) out[idx] = bil_b[idx % cC];
}

// Kernel 6b: bilinear classifier, fused outer-product GEMM.
// out[n][c] += sum_{i,j} hs[n][64kb+i]*ts[n][64kb+j]*W[(64kb+i)*64+j][c]
// grid (62 n-tiles, 12 k-blocks), block 256 (tx=c-lane 0..15, ty=n-lane 0..15).
__global__ void bil_k(const float* __restrict__ hsp, const float* __restrict__ tsp,
                      const float* __restrict__ W, float* __restrict__ out) {
    int n0 = blockIdx.x * 64;
    int kb = blockIdx.y;  // 0..11
    int tid = threadIdx.x, tx = tid % 16, ty = tid / 16;
    __shared__ float Hs[64][65];
    __shared__ float Ts[64][65];
    __shared__ float Ws[64 * 112];
    for (int i = 0; i < 16; i++) {
        int idx = tid + i * 256;  // 0..4095
        int row = idx >> 6, j = idx & 63;
        Hs[row][j] = hsp[(size_t)(n0 + row) * cEMB + kb * 64 + j];
        Ts[row][j] = tsp[(size_t)(n0 + row) * cEMB + kb * 64 + j];
    }
    // zero the pad columns once; loads below only touch c < 97
    for (int idx = tid; idx < 64 * 112; idx += 256) Ws[idx] = 0.f;
    __syncthreads();
    float acc[4][7] = {};
    for (int i = 0; i < 64; i++) {
        const float* wp = W + ((size_t)kb * 4096 + i * 64) * cC;
        __syncthreads();  // previous iteration's Ws reads done
        for (int t = tid; t < 64 * cC; t += 256) {
            int j = t / cC, c = t % cC;
            Ws[j * 112 + c] = wp[t];
        }
        __syncthreads();
        float hv[4];
        for (int nn = 0; nn < 4; nn++) hv[nn] = Hs[ty + 16 * nn][i];
        for (int j = 0; j < 64; j++) {
            float wv[7];
#pragma unroll
            for (int cc = 0; cc < 7; cc++) wv[cc] = Ws[j * 112 + tx + 16 * cc];
#pragma unroll
            for (int nn = 0; nn < 4; nn++) {
                float p = hv[nn] * Ts[ty + 16 * nn][j];
#pragma unroll
                for (int cc = 0; cc < 7; cc++) acc[nn][cc] += p * wv[cc];
            }
        }
    }
    for (int nn = 0; nn < 4; nn++) {
        int n = n0 + ty + 16 * nn;
        for (int cc = 0; cc < 7; cc++) {
            int c = tx + 16 * cc;
            if (c < cC) atomicAdd(&out[(size_t)n * cC + c], acc[nn][cc]);
        }
    }
}

// ---------------------------------------------------------------------------
extern "C" void kernel_launch(void* const* d_in, const int* in_sizes, int n_in,
                              void* d_out, int out_size, void* d_ws, size_t ws_size,
                              hipStream_t stream) {
    const float* seq_lhs  = (const float*)d_in[0];
    const float* ent_lhs  = (const float*)d_in[1];
    const float* attn     = (const float*)d_in[2];
    const int*   ids      = (const int*)d_in[3];
    const int*   hts      = (const int*)d_in[4];
    const float* head_W   = (const float*)d_in[5];
    const float* head_b   = (const float*)d_in[6];
    const float* tail_W   = (const float*)d_in[7];
    const float* tail_b   = (const float*)d_in[8];
    const float* bil_W    = (const float*)d_in[9];
    const float* bil_b    = (const float*)d_in[10];
    float* out = (float*)d_out;

    // workspace layout (floats)
    float* ws = (float*)d_ws;
    int*   counts   = (int*)ws;                       // 128 ints
    float* ent_emb  = ws + 128;                       // 4*32*1024   = 131072
    float* ent_attn = ent_emb + (size_t)cB * cE * cH; // 4*32*16*1024= 2097152
    float* wbuf     = ent_attn + (size_t)cB * cE * cA * cL; // 4*992*1024
    float* rel      = wbuf + (size_t)cN * cL;         // 4*992*1024
    float* hsp      = rel + (size_t)cN * cH;          // 3968*768
    float* tsp      = hsp + (size_t)cN * cEMB;        // 3968*768

    hipLaunchKernelGGL(ent_pool_k, dim3(cE, cB), dim3(256), 0, stream,
                       ent_lhs, ids, ent_emb, counts);
    hipLaunchKernelGGL(ent_attn_k, dim3(cB * cA, cL / 256), dim3(256), 0, stream,
                       attn, ids, counts, ent_attn);
    hipLaunchKernelGGL(w_k, dim3(cN), dim3(256), 0, stream,
                       ent_attn, hts, wbuf);
    hipLaunchKernelGGL(rel_gemm_k, dim3(16, 16, cB), dim3(256), 0, stream,
                       wbuf, seq_lhs, rel);
    hipLaunchKernelGGL(proj_k, dim3(cN / 64, cEMB / 64), dim3(256), 0, stream,
                       ent_emb, rel, hts, head_W, head_b, hsp, 0);
    hipLaunchKernelGGL(proj_k, dim3(cN / 64, cEMB / 64), dim3(256), 0, stream,
                       ent_emb, rel, hts, tail_W, tail_b, tsp, 1);
    hipLaunchKernelGGL(out_init_k, dim3((cN * cC + 255) / 256), dim3(256), 0, stream,
                       bil_b, out);
    hipLaunchKernelGGL(bil_k, dim3(cN / 64, 12), dim3(256), 0, stream,
                       hsp, tsp, bil_W, out);
}

// Round 2
// 1212.079 us; speedup vs baseline: 2.1012x; 2.1012x over previous
//
#include <hip/hip_runtime.h>
#include <hip/hip_bf16.h>
#include <math.h>

// Problem constants
constexpr int cB   = 4;
constexpr int cL   = 1024;
constexpr int cH   = 1024;
constexpr int cA   = 16;
constexpr int cM   = 128;
constexpr int cE   = 32;
constexpr int cR   = 992;
constexpr int cEMB = 768;
constexpr int cC   = 97;
constexpr int cN   = cB * cR;  // 3968
constexpr int cK   = cEMB * 64; // 49152 bilinear K

typedef unsigned short ushort;
typedef __attribute__((ext_vector_type(8))) short short8;
typedef __attribute__((ext_vector_type(4))) float float4v;

static __device__ inline float bf2f(ushort u) {
    unsigned v = ((unsigned)u) << 16;
    float f;
    __builtin_memcpy(&f, &v, 4);
    return f;
}
static __device__ inline ushort f2bf(float f) {
    unsigned u;
    __builtin_memcpy(&u, &f, 4);
    unsigned r = (u + 0x7FFFu + ((u >> 16) & 1u)) >> 16;
    return (ushort)r;
}

// ---------------------------------------------------------------------------
// Kernel 1: per-(b,e) logsumexp pooling of ent_lhs over mentions + counts
__global__ void ent_pool_k(const float* __restrict__ ent_lhs, const int* __restrict__ ids,
                           float* __restrict__ ent_emb, int* __restrict__ counts) {
    int e = blockIdx.x, b = blockIdx.y;
    __shared__ int sid[cM];
    int tid = threadIdx.x;
    if (tid < cM) sid[tid] = ids[b * cM + tid];
    __syncthreads();
    int cnt = 0;
    for (int m = 0; m < cM; m++) cnt += (sid[m] == e) ? 1 : 0;
    if (tid == 0) counts[b * cE + e] = cnt;
    for (int h = tid; h < cH; h += 256) {
        float mx = -1e30f;
        for (int m = 0; m < cM; m++)
            if (sid[m] == e) mx = fmaxf(mx, ent_lhs[(size_t)(b * cM + m) * cH + h]);
        float s = 0.f;
        for (int m = 0; m < cM; m++)
            if (sid[m] == e) s += __expf(ent_lhs[(size_t)(b * cM + m) * cH + h] - mx);
        ent_emb[(size_t)(b * cE + e) * cH + h] = (cnt > 0) ? (mx + __logf(s)) : 0.f;
    }
}

// ---------------------------------------------------------------------------
// Kernel 2: ent_attn[b][e][a][l] = sum_{m: ids==e} attn[b][a][m][l] / max(count,1)
__global__ void ent_attn_k(const float* __restrict__ attn, const int* __restrict__ ids,
                           const int* __restrict__ counts, float* __restrict__ ent_attn) {
    int ba = blockIdx.x;
    int b = ba / cA, a = ba % cA;
    int tid = threadIdx.x;
    int l = blockIdx.y * 256 + tid;
    __shared__ int sid[cM];
    __shared__ int scnt[cE];
    __shared__ float sacc[256 * 33];
    if (tid < cM) sid[tid] = ids[b * cM + tid];
    if (tid < cE) scnt[tid] = counts[b * cE + tid];
    float* acc = &sacc[tid * 33];
    for (int e2 = 0; e2 < cE; e2++) acc[e2] = 0.f;
    __syncthreads();
    const float* ap = attn + ((size_t)(b * cA + a) * cM) * cL + l;
    for (int m = 0; m < cM; m++) acc[sid[m]] += ap[(size_t)m * cL];
    for (int e2 = 0; e2 < cE; e2++) {
        ent_attn[((size_t)(b * cE + e2) * cA + a) * cL + l] =
            acc[e2] / (float)max(scnt[e2], 1);
    }
}

// ---------------------------------------------------------------------------
// Kernel 3: w[b][r][l] = mean_a ha*ta, normalized over l.  grid cN, block 256
__global__ void w_k(const float* __restrict__ ent_attn, const int* __restrict__ hts,
                    float* __restrict__ w) {
    int nr = blockIdx.x;
    int b = nr / cR;
    int he = hts[nr * 2 + 0], te = hts[nr * 2 + 1];
    int tid = threadIdx.x;
    const float* ha = ent_attn + ((size_t)(b * cE + he) * cA) * cL;
    const float* ta = ent_attn + ((size_t)(b * cE + te) * cA) * cL;
    float v[4];
    float psum = 0.f;
    for (int i = 0; i < 4; i++) {
        int l = tid + i * 256;
        float s = 0.f;
        for (int a = 0; a < cA; a++) s += ha[(size_t)a * cL + l] * ta[(size_t)a * cL + l];
        s *= (1.0f / cA);
        v[i] = s;
        psum += s;
    }
    for (int off = 32; off > 0; off >>= 1) psum += __shfl_down(psum, off, 64);
    __shared__ float red[4];
    if ((tid & 63) == 0) red[tid >> 6] = psum;
    __syncthreads();
    float tot = red[0] + red[1] + red[2] + red[3];
    float inv = 1.0f / (tot + 1e-5f);
    for (int i = 0; i < 4; i++) w[(size_t)nr * cL + tid + i * 256] = v[i] * inv;
}

// ---------------------------------------------------------------------------
// Kernel 4: rel[b][r][h] = sum_l w[b][r][l] * seq[b][l][h]  (f32 tiled)
__global__ void rel_gemm_k(const float* __restrict__ w, const float* __restrict__ seq,
                           float* __restrict__ rel) {
    int b = blockIdx.z;
    int r0 = blockIdx.x * 64, h0 = blockIdx.y * 64;
    int tid = threadIdx.x, tx = tid % 16, ty = tid / 16;
    __shared__ float As[64][17];
    __shared__ float Bs[16][68];
    float acc[4][4] = {};
    for (int kt = 0; kt < cL; kt += 16) {
        for (int i = 0; i < 4; i++) {
            int rr = ty + i * 16;
            int r = r0 + rr;
            As[rr][tx] = (r < cR) ? w[((size_t)b * cR + r) * cL + kt + tx] : 0.f;
        }
        for (int i = 0; i < 4; i++) {
            int hh = tx + i * 16;
            Bs[ty][hh] = seq[((size_t)b * cL + kt + ty) * cH + h0 + hh];
        }
        __syncthreads();
#pragma unroll
        for (int k = 0; k < 16; k++) {
            float av[4], bv[4];
            for (int i = 0; i < 4; i++) av[i] = As[ty + 16 * i][k];
            for (int j = 0; j < 4; j++) bv[j] = Bs[k][tx + 16 * j];
            for (int i = 0; i < 4; i++)
                for (int j = 0; j < 4; j++) acc[i][j] += av[i] * bv[j];
        }
        __syncthreads();
    }
    for (int i = 0; i < 4; i++) {
        int r = r0 + ty + 16 * i;
        if (r < cR)
            for (int j = 0; j < 4; j++)
                rel[((size_t)b * cR + r) * cH + h0 + tx + 16 * j] = acc[i][j];
    }
}

// ---------------------------------------------------------------------------
// Kernel 5: projection GEMM (f32), now writes bf16 output for the MFMA bilinear
__global__ void proj_k(const float* __restrict__ ent_emb, const float* __restrict__ rel,
                       const int* __restrict__ hts, const float* __restrict__ W,
                       const float* __restrict__ bias, ushort* __restrict__ outp, int sel) {
    int n0 = blockIdx.x * 64, e0 = blockIdx.y * 64;
    int tid = threadIdx.x, tx = tid % 16, ty = tid / 16;
    __shared__ int sbase[64];
    if (tid < 64) {
        int n = n0 + tid;
        int b = n / cR;
        int ent = hts[n * 2 + sel];
        sbase[tid] = (b * cE + ent) * cH;
    }
    __shared__ float As[64][17];
    __shared__ float Bs[16][68];
    float acc[4][4] = {};
    __syncthreads();
    for (int kt = 0; kt < 2 * cH; kt += 16) {
        bool first = kt < cH;
        for (int i = 0; i < 4; i++) {
            int rr = ty + i * 16;
            int n = n0 + rr;
            As[rr][tx] = first ? ent_emb[(size_t)sbase[rr] + kt + tx]
                               : rel[(size_t)n * cH + kt - cH + tx];
        }
        for (int i = 0; i < 4; i++) {
            int ee = tx + i * 16;
            Bs[ty][ee] = W[(size_t)(kt + ty) * cEMB + e0 + ee];
        }
        __syncthreads();
#pragma unroll
        for (int k = 0; k < 16; k++) {
            float av[4], bv[4];
            for (int i = 0; i < 4; i++) av[i] = As[ty + 16 * i][k];
            for (int j = 0; j < 4; j++) bv[j] = Bs[k][tx + 16 * j];
            for (int i = 0; i < 4; i++)
                for (int j = 0; j < 4; j++) acc[i][j] += av[i] * bv[j];
        }
        __syncthreads();
    }
    for (int i = 0; i < 4; i++) {
        int n = n0 + ty + 16 * i;
        for (int j = 0; j < 4; j++) {
            int ee = e0 + tx + 16 * j;
            outp[(size_t)n * cEMB + ee] = f2bf(tanhf(acc[i][j] + bias[ee]));
        }
    }
}

// ---------------------------------------------------------------------------
// Kernel 6a: transpose bil_W [49152][97] f32 -> WT [112][49152] bf16 (pad cols zero)
__global__ void wt_transpose_k(const float* __restrict__ W, ushort* __restrict__ WT) {
    int k0 = blockIdx.x * 32, c0 = blockIdx.y * 32;
    int tx = threadIdx.x & 31, ty = threadIdx.x >> 5;  // ty 0..7
    __shared__ float tile[32][33];
    for (int p = 0; p < 4; p++) {
        int r = ty + p * 8;
        int c = c0 + tx;
        tile[r][tx] = (c < cC) ? W[(size_t)(k0 + r) * cC + c] : 0.f;
    }
    __syncthreads();
    for (int p = 0; p < 4; p++) {
        int rw = ty + p * 8;
        int c = c0 + rw;
        if (c < 112) WT[(size_t)c * cK + k0 + tx] = f2bf(tile[tx][rw]);
    }
}

// Kernel 6b: out init with bias
__global__ void out_init_k(const float* __restrict__ bil_b, float* __restrict__ out) {
    int idx = blockIdx.x * 256 + threadIdx.x;
    if (idx < cN * cC) out[idx] = bil_b[idx % cC];
}

// ---------------------------------------------------------------------------
// Kernel 6c: MFMA bilinear.  out[n][c] += sum_{i,j} hs[n][kb*64+i]*ts[n][kb*64+j]
//                                          * W[(kb*64+i)*64+j][c]
// A (on-the-fly): A[m=lane&15][k=(lane>>4)*8+jj]  (verified layout)
// B from WT[c][k]: B[k=(lane>>4)*8+jj][c=lane&15]
// C/D: col=lane&15, row=(lane>>4)*4+reg          (verified layout)
// Block: 128 rows x 112 cols, K-slice = 2048 (half a kb). grid (31, 24).
__global__ __launch_bounds__(256) void
bil_mfma_k(const ushort* __restrict__ hsp, const ushort* __restrict__ tsp,
           const ushort* __restrict__ WT, float* __restrict__ out) {
    const int n0 = blockIdx.x * 128;
    const int kb = blockIdx.y >> 1;        // 0..11
    const int ibase = (blockIdx.y & 1) * 32;  // i-half within kb
    const int tid = threadIdx.x;
    const int lane = tid & 63;
    const int wv = tid >> 6;               // 0..3
    const int col = lane & 15;
    const int g = lane >> 4;               // 0..3
    const int wbase = wv * 32;             // wave's row base in block tile

    __shared__ ushort sH[128 * 40];        // hs rows, 32 i-cols, stride 40 (pad)
    __shared__ ushort sT[128 * 72];        // ts rows, 64 j-cols, stride 72 (pad)
    __shared__ ushort sW[2][112 * 72];     // WT tile per i, double-buffered

    // stage hs (128 rows x 32), ts (128 rows x 64)
    for (int t = tid; t < 512; t += 256) {
        int row = t >> 2, seg = t & 3;
        *(short8*)&sH[row * 40 + seg * 8] =
            *(const short8*)&hsp[(size_t)(n0 + row) * cEMB + kb * 64 + ibase + seg * 8];
    }
    for (int t = tid; t < 1024; t += 256) {
        int row = t >> 3, seg = t & 7;
        *(short8*)&sT[row * 72 + seg * 8] =
            *(const short8*)&tsp[(size_t)(n0 + row) * cEMB + kb * 64 + seg * 8];
    }
    // stage W tile for first i
    {
        const size_t ksrc = (size_t)kb * 4096 + (size_t)ibase * 64;
        for (int t = tid; t < 896; t += 256) {
            int c = t >> 3, seg = t & 7;
            *(short8*)&sW[0][c * 72 + seg * 8] =
                *(const short8*)&WT[(size_t)c * cK + ksrc + seg * 8];
        }
    }
    __syncthreads();

    float4v acc[2][7];
#pragma unroll
    for (int mt = 0; mt < 2; mt++)
#pragma unroll
        for (int ct = 0; ct < 7; ct++)
            acc[mt][ct] = (float4v){0.f, 0.f, 0.f, 0.f};

    for (int ii = 0; ii < 32; ii++) {
        const int buf = ii & 1;
        // prefetch next i's W tile into the other buffer
        if (ii + 1 < 32) {
            const size_t ksrc = (size_t)kb * 4096 + (size_t)(ibase + ii + 1) * 64;
            for (int t = tid; t < 896; t += 256) {
                int c = t >> 3, seg = t & 7;
                *(short8*)&sW[buf ^ 1][c * 72 + seg * 8] =
                    *(const short8*)&WT[(size_t)c * cK + ksrc + seg * 8];
            }
        }
        // compute with current buffer
        const ushort* sWb = sW[buf];
        float h0 = bf2f(sH[(wbase + col) * 40 + ii]);
        float h1 = bf2f(sH[(wbase + 16 + col) * 40 + ii]);
#pragma unroll
        for (int j0 = 0; j0 < 64; j0 += 32) {
            short8 t0 = *(const short8*)&sT[(wbase + col) * 72 + j0 + g * 8];
            short8 t1 = *(const short8*)&sT[(wbase + 16 + col) * 72 + j0 + g * 8];
            short8 a0, a1;
#pragma unroll
            for (int jj = 0; jj < 8; jj++) {
                a0[jj] = (short)f2bf(h0 * bf2f((ushort)t0[jj]));
                a1[jj] = (short)f2bf(h1 * bf2f((ushort)t1[jj]));
            }
#pragma unroll
            for (int ct = 0; ct < 7; ct++) {
                short8 bfr = *(const short8*)&sWb[(ct * 16 + col) * 72 + j0 + g * 8];
                acc[0][ct] = __builtin_amdgcn_mfma_f32_16x16x32_bf16(a0, bfr, acc[0][ct], 0, 0, 0);
                acc[1][ct] = __builtin_amdgcn_mfma_f32_16x16x32_bf16(a1, bfr, acc[1][ct], 0, 0, 0);
            }
        }
        __syncthreads();
    }

    // epilogue: atomic combine (24 K-slices per output element)
#pragma unroll
    for (int mt = 0; mt < 2; mt++) {
#pragma unroll
        for (int ct = 0; ct < 7; ct++) {
            int c = ct * 16 + col;
            if (c < cC) {
                int rowb = n0 + wbase + mt * 16 + g * 4;
#pragma unroll
                for (int reg = 0; reg < 4; reg++)
                    atomicAdd(&out[(size_t)(rowb + reg) * cC + c], acc[mt][ct][reg]);
            }
        }
    }
}

// ---------------------------------------------------------------------------
extern "C" void kernel_launch(void* const* d_in, const int* in_sizes, int n_in,
                              void* d_out, int out_size, void* d_ws, size_t ws_size,
                              hipStream_t stream) {
    const float* seq_lhs  = (const float*)d_in[0];
    const float* ent_lhs  = (const float*)d_in[1];
    const float* attn     = (const float*)d_in[2];
    const int*   ids      = (const int*)d_in[3];
    const int*   hts      = (const int*)d_in[4];
    const float* head_W   = (const float*)d_in[5];
    const float* head_b   = (const float*)d_in[6];
    const float* tail_W   = (const float*)d_in[7];
    const float* tail_b   = (const float*)d_in[8];
    const float* bil_W    = (const float*)d_in[9];
    const float* bil_b    = (const float*)d_in[10];
    float* out = (float*)d_out;

    // workspace layout
    float* ws = (float*)d_ws;
    int*    counts   = (int*)ws;                            // 128 ints
    float*  ent_emb  = ws + 128;                            // 131072 f
    float*  ent_attn = ent_emb + (size_t)cB * cE * cH;      // 2097152 f
    float*  wbuf     = ent_attn + (size_t)cB * cE * cA * cL;// 4063232 f
    float*  rel      = wbuf + (size_t)cN * cL;              // 4063232 f
    ushort* hsp      = (ushort*)(rel + (size_t)cN * cH);    // 3047424 u16
    ushort* tsp      = hsp + (size_t)cN * cEMB;             // 3047424 u16
    ushort* WT       = tsp + (size_t)cN * cEMB;             // 112*49152 u16

    hipLaunchKernelGGL(wt_transpose_k, dim3(cK / 32, 4), dim3(256), 0, stream,
                       bil_W, WT);
    hipLaunchKernelGGL(ent_pool_k, dim3(cE, cB), dim3(256), 0, stream,
                       ent_lhs, ids, ent_emb, counts);
    hipLaunchKernelGGL(ent_attn_k, dim3(cB * cA, cL / 256), dim3(256), 0, stream,
                       attn, ids, counts, ent_attn);
    hipLaunchKernelGGL(w_k, dim3(cN), dim3(256), 0, stream,
                       ent_attn, hts, wbuf);
    hipLaunchKernelGGL(rel_gemm_k, dim3(16, 16, cB), dim3(256), 0, stream,
                       wbuf, seq_lhs, rel);
    hipLaunchKernelGGL(proj_k, dim3(cN / 64, cEMB / 64), dim3(256), 0, stream,
                       ent_emb, rel, hts, head_W, head_b, hsp, 0);
    hipLaunchKernelGGL(proj_k, dim3(cN / 64, cEMB / 64), dim3(256), 0, stream,
                       ent_emb, rel, hts, tail_W, tail_b, tsp, 1);
    hipLaunchKernelGGL(out_init_k, dim3((cN * cC + 255) / 256), dim3(256), 0, stream,
                       bil_b, out);
    hipLaunchKernelGGL(bil_mfma_k, dim3(cN / 128, 24), dim3(256), 0, stream,
                       hsp, tsp, WT, out);
}

// Round 3
// 574.848 us; speedup vs baseline: 4.4304x; 2.1085x over previous
//
#include <hip/hip_runtime.h>
#include <hip/hip_bf16.h>
#include <math.h>

// Problem constants
constexpr int cB   = 4;
constexpr int cL   = 1024;
constexpr int cH   = 1024;
constexpr int cA   = 16;
constexpr int cM   = 128;
constexpr int cE   = 32;
constexpr int cR   = 992;
constexpr int cEMB = 768;
constexpr int cC   = 97;
constexpr int cN   = cB * cR;   // 3968
constexpr int cK   = cEMB * 64; // 49152 bilinear K

typedef unsigned short ushort;
typedef __attribute__((ext_vector_type(8))) short short8;
typedef __attribute__((ext_vector_type(4))) float float4v;

static __device__ inline float bf2f(ushort u) {
    unsigned v = ((unsigned)u) << 16;
    float f;
    __builtin_memcpy(&f, &v, 4);
    return f;
}
static __device__ inline ushort f2bf(float f) {
    unsigned u;
    __builtin_memcpy(&u, &f, 4);
    unsigned r = (u + 0x7FFFu + ((u >> 16) & 1u)) >> 16;
    return (ushort)r;
}

// ---------------------------------------------------------------------------
// Generic transpose f32 -> bf16: src[z][R][C] -> dst[z][Cp][R], zero-pad c>=C
__global__ void tr_bf16_k(const float* __restrict__ src, ushort* __restrict__ dst,
                          int R, int C, int Cp) {
    int z = blockIdx.z;
    int r0 = blockIdx.x * 32, c0 = blockIdx.y * 32;
    int tx = threadIdx.x & 31, ty = threadIdx.x >> 5;  // ty 0..7
    __shared__ float tile[32][33];
    for (int p = 0; p < 4; p++) {
        int r = r0 + ty + p * 8, c = c0 + tx;
        tile[ty + p * 8][tx] = (r < R && c < C) ? src[((size_t)z * R + r) * C + c] : 0.f;
    }
    __syncthreads();
    for (int p = 0; p < 4; p++) {
        int c = c0 + ty + p * 8, r = r0 + tx;
        if (c < Cp && r < R)
            dst[((size_t)z * Cp + c) * R + r] = f2bf(tile[tx][ty + p * 8]);
    }
}

// ---------------------------------------------------------------------------
// Kernel 1: per-(b,e) logsumexp pooling of ent_lhs; writes bf16
__global__ void ent_pool_k(const float* __restrict__ ent_lhs, const int* __restrict__ ids,
                           ushort* __restrict__ ent_emb, int* __restrict__ counts) {
    int e = blockIdx.x, b = blockIdx.y;
    __shared__ int sid[cM];
    int tid = threadIdx.x;
    if (tid < cM) sid[tid] = ids[b * cM + tid];
    __syncthreads();
    int cnt = 0;
    for (int m = 0; m < cM; m++) cnt += (sid[m] == e) ? 1 : 0;
    if (tid == 0) counts[b * cE + e] = cnt;
    for (int h = tid; h < cH; h += 256) {
        float mx = -1e30f;
        for (int m = 0; m < cM; m++)
            if (sid[m] == e) mx = fmaxf(mx, ent_lhs[(size_t)(b * cM + m) * cH + h]);
        float s = 0.f;
        for (int m = 0; m < cM; m++)
            if (sid[m] == e) s += __expf(ent_lhs[(size_t)(b * cM + m) * cH + h] - mx);
        ent_emb[(size_t)(b * cE + e) * cH + h] = f2bf((cnt > 0) ? (mx + __logf(s)) : 0.f);
    }
}

// ---------------------------------------------------------------------------
// Kernel 2: ent_attn[b][e][a][l] = sum_{m: ids==e} attn[b][a][m][l] / max(count,1)
__global__ void ent_attn_k(const float* __restrict__ attn, const int* __restrict__ ids,
                           const int* __restrict__ counts, float* __restrict__ ent_attn) {
    int ba = blockIdx.x;
    int b = ba / cA, a = ba % cA;
    int tid = threadIdx.x;
    int l = blockIdx.y * 256 + tid;
    __shared__ int sid[cM];
    __shared__ int scnt[cE];
    __shared__ float sacc[256 * 33];
    if (tid < cM) sid[tid] = ids[b * cM + tid];
    if (tid < cE) scnt[tid] = counts[b * cE + tid];
    float* acc = &sacc[tid * 33];
    for (int e2 = 0; e2 < cE; e2++) acc[e2] = 0.f;
    __syncthreads();
    const float* ap = attn + ((size_t)(b * cA + a) * cM) * cL + l;
    for (int m = 0; m < cM; m++) acc[sid[m]] += ap[(size_t)m * cL];
    for (int e2 = 0; e2 < cE; e2++) {
        ent_attn[((size_t)(b * cE + e2) * cA + a) * cL + l] =
            acc[e2] / (float)max(scnt[e2], 1);
    }
}

// ---------------------------------------------------------------------------
// Kernel 3: w[b][r][l] = mean_a ha*ta, normalized over l; writes bf16
__global__ void w_k(const float* __restrict__ ent_attn, const int* __restrict__ hts,
                    ushort* __restrict__ w) {
    int nr = blockIdx.x;
    int b = nr / cR;
    int he = hts[nr * 2 + 0], te = hts[nr * 2 + 1];
    int tid = threadIdx.x;
    const float* ha = ent_attn + ((size_t)(b * cE + he) * cA) * cL;
    const float* ta = ent_attn + ((size_t)(b * cE + te) * cA) * cL;
    float v[4];
    float psum = 0.f;
    for (int i = 0; i < 4; i++) {
        int l = tid + i * 256;
        float s = 0.f;
        for (int a = 0; a < cA; a++) s += ha[(size_t)a * cL + l] * ta[(size_t)a * cL + l];
        s *= (1.0f / cA);
        v[i] = s;
        psum += s;
    }
    for (int off = 32; off > 0; off >>= 1) psum += __shfl_down(psum, off, 64);
    __shared__ float red[4];
    if ((tid & 63) == 0) red[tid >> 6] = psum;
    __syncthreads();
    float tot = red[0] + red[1] + red[2] + red[3];
    float inv = 1.0f / (tot + 1e-5f);
    for (int i = 0; i < 4; i++) w[(size_t)nr * cL + tid + i * 256] = f2bf(v[i] * inv);
}

// ---------------------------------------------------------------------------
// Kernel 4: rel MFMA GEMM: rel[n][h] = sum_l w[n][l] * seqT[b][h][l]
// Tile 128(M) x 64(N), BK=64, 4 waves each 32 rows x 64 cols.
// grid (8, 16, cB); M=992 per b -> row guard on last tile.
__global__ __launch_bounds__(256) void
rel_mfma_k(const ushort* __restrict__ wbf, const ushort* __restrict__ seqT,
           ushort* __restrict__ relbf) {
    const int b = blockIdx.z;
    const int r0 = blockIdx.x * 128, h0 = blockIdx.y * 64;
    const int tid = threadIdx.x, lane = tid & 63, wv = tid >> 6;
    const int col = lane & 15, g = lane >> 4;

    __shared__ ushort sA[128 * 72];
    __shared__ ushort sB[64 * 72];

    float4v acc[2][4];
#pragma unroll
    for (int mt = 0; mt < 2; mt++)
#pragma unroll
        for (int ct = 0; ct < 4; ct++) acc[mt][ct] = (float4v){0.f, 0.f, 0.f, 0.f};

    for (int kt = 0; kt < cL; kt += 64) {
#pragma unroll
        for (int p = 0; p < 4; p++) {
            int t = tid + p * 256;
            int row = t >> 3, seg = t & 7;
            int r = min(r0 + row, cR - 1);
            *(short8*)&sA[row * 72 + seg * 8] =
                *(const short8*)&wbf[((size_t)b * cR + r) * cL + kt + seg * 8];
        }
#pragma unroll
        for (int p = 0; p < 2; p++) {
            int t = tid + p * 256;
            int c = t >> 3, seg = t & 7;
            *(short8*)&sB[c * 72 + seg * 8] =
                *(const short8*)&seqT[((size_t)b * cH + h0 + c) * cL + kt + seg * 8];
        }
        __syncthreads();
        const int wrow = wv * 32;
#pragma unroll
        for (int k0 = 0; k0 < 64; k0 += 32) {
            short8 a0 = *(const short8*)&sA[(wrow + col) * 72 + k0 + g * 8];
            short8 a1 = *(const short8*)&sA[(wrow + 16 + col) * 72 + k0 + g * 8];
#pragma unroll
            for (int ct = 0; ct < 4; ct++) {
                short8 bf = *(const short8*)&sB[(ct * 16 + col) * 72 + k0 + g * 8];
                acc[0][ct] = __builtin_amdgcn_mfma_f32_16x16x32_bf16(a0, bf, acc[0][ct], 0, 0, 0);
                acc[1][ct] = __builtin_amdgcn_mfma_f32_16x16x32_bf16(a1, bf, acc[1][ct], 0, 0, 0);
            }
        }
        __syncthreads();
    }
#pragma unroll
    for (int mt = 0; mt < 2; mt++) {
#pragma unroll
        for (int ct = 0; ct < 4; ct++) {
            int h = h0 + ct * 16 + col;
            int rowb = r0 + wv * 32 + mt * 16 + g * 4;
#pragma unroll
            for (int reg = 0; reg < 4; reg++) {
                int r = rowb + reg;
                if (r < cR)
                    relbf[((size_t)b * cR + r) * cH + h] = f2bf(acc[mt][ct][reg]);
            }
        }
    }
}

// ---------------------------------------------------------------------------
// Kernel 5: projection MFMA GEMM with gathered A:
// out[n][e] = tanh( sum_k concat(ent_emb[gather], rel)[n][k] * W[k][e] + b[e] )
// Tile 128 x 64, BK=64. grid (31, 12). Writes bf16.
__global__ __launch_bounds__(256) void
proj_mfma_k(const ushort* __restrict__ ent_bf, const ushort* __restrict__ relbf,
            const int* __restrict__ hts, const ushort* __restrict__ WTp,
            const float* __restrict__ bias, ushort* __restrict__ outp, int sel) {
    const int n0 = blockIdx.x * 128, e0 = blockIdx.y * 64;
    const int tid = threadIdx.x, lane = tid & 63, wv = tid >> 6;
    const int col = lane & 15, g = lane >> 4;

    __shared__ int sbase[128];
    __shared__ ushort sA[128 * 72];
    __shared__ ushort sB[64 * 72];

    if (tid < 128) {
        int n = n0 + tid, bb = n / cR;
        sbase[tid] = (bb * cE + hts[n * 2 + sel]) * cH;
    }
    __syncthreads();

    float4v acc[2][4];
#pragma unroll
    for (int mt = 0; mt < 2; mt++)
#pragma unroll
        for (int ct = 0; ct < 4; ct++) acc[mt][ct] = (float4v){0.f, 0.f, 0.f, 0.f};

    for (int kt = 0; kt < 2 * cH; kt += 64) {
        const bool first = kt < cH;
#pragma unroll
        for (int p = 0; p < 4; p++) {
            int t = tid + p * 256;
            int row = t >> 3, seg = t & 7;
            const ushort* src = first
                ? &ent_bf[(size_t)sbase[row] + kt + seg * 8]
                : &relbf[(size_t)(n0 + row) * cH + (kt - cH) + seg * 8];
            *(short8*)&sA[row * 72 + seg * 8] = *(const short8*)src;
        }
#pragma unroll
        for (int p = 0; p < 2; p++) {
            int t = tid + p * 256;
            int c = t >> 3, seg = t & 7;
            *(short8*)&sB[c * 72 + seg * 8] =
                *(const short8*)&WTp[(size_t)(e0 + c) * (2 * cH) + kt + seg * 8];
        }
        __syncthreads();
        const int wrow = wv * 32;
#pragma unroll
        for (int k0 = 0; k0 < 64; k0 += 32) {
            short8 a0 = *(const short8*)&sA[(wrow + col) * 72 + k0 + g * 8];
            short8 a1 = *(const short8*)&sA[(wrow + 16 + col) * 72 + k0 + g * 8];
#pragma unroll
            for (int ct = 0; ct < 4; ct++) {
                short8 bf = *(const short8*)&sB[(ct * 16 + col) * 72 + k0 + g * 8];
                acc[0][ct] = __builtin_amdgcn_mfma_f32_16x16x32_bf16(a0, bf, acc[0][ct], 0, 0, 0);
                acc[1][ct] = __builtin_amdgcn_mfma_f32_16x16x32_bf16(a1, bf, acc[1][ct], 0, 0, 0);
            }
        }
        __syncthreads();
    }
#pragma unroll
    for (int mt = 0; mt < 2; mt++) {
#pragma unroll
        for (int ct = 0; ct < 4; ct++) {
            int e = e0 + ct * 16 + col;
            float bv = bias[e];
            int rowb = n0 + wv * 32 + mt * 16 + g * 4;
#pragma unroll
            for (int reg = 0; reg < 4; reg++)
                outp[(size_t)(rowb + reg) * cEMB + e] = f2bf(tanhf(acc[mt][ct][reg] + bv));
        }
    }
}

// ---------------------------------------------------------------------------
// Kernel 6a: out init with bias
__global__ void out_init_k(const float* __restrict__ bil_b, float* __restrict__ out) {
    int idx = blockIdx.x * 256 + threadIdx.x;
    if (idx < cN * cC) out[idx] = bil_b[idx % cC];
}

// ---------------------------------------------------------------------------
// Kernel 6b: MFMA bilinear (unchanged from round 1 — verified layouts)
__global__ __launch_bounds__(256) void
bil_mfma_k(const ushort* __restrict__ hsp, const ushort* __restrict__ tsp,
           const ushort* __restrict__ WT, float* __restrict__ out) {
    const int n0 = blockIdx.x * 128;
    const int kb = blockIdx.y >> 1;
    const int ibase = (blockIdx.y & 1) * 32;
    const int tid = threadIdx.x;
    const int lane = tid & 63;
    const int wv = tid >> 6;
    const int col = lane & 15;
    const int g = lane >> 4;
    const int wbase = wv * 32;

    __shared__ ushort sH[128 * 40];
    __shared__ ushort sT[128 * 72];
    __shared__ ushort sW[2][112 * 72];

    for (int t = tid; t < 512; t += 256) {
        int row = t >> 2, seg = t & 3;
        *(short8*)&sH[row * 40 + seg * 8] =
            *(const short8*)&hsp[(size_t)(n0 + row) * cEMB + kb * 64 + ibase + seg * 8];
    }
    for (int t = tid; t < 1024; t += 256) {
        int row = t >> 3, seg = t & 7;
        *(short8*)&sT[row * 72 + seg * 8] =
            *(const short8*)&tsp[(size_t)(n0 + row) * cEMB + kb * 64 + seg * 8];
    }
    {
        const size_t ksrc = (size_t)kb * 4096 + (size_t)ibase * 64;
        for (int t = tid; t < 896; t += 256) {
            int c = t >> 3, seg = t & 7;
            *(short8*)&sW[0][c * 72 + seg * 8] =
                *(const short8*)&WT[(size_t)c * cK + ksrc + seg * 8];
        }
    }
    __syncthreads();

    float4v acc[2][7];
#pragma unroll
    for (int mt = 0; mt < 2; mt++)
#pragma unroll
        for (int ct = 0; ct < 7; ct++)
            acc[mt][ct] = (float4v){0.f, 0.f, 0.f, 0.f};

    for (int ii = 0; ii < 32; ii++) {
        const int buf = ii & 1;
        if (ii + 1 < 32) {
            const size_t ksrc = (size_t)kb * 4096 + (size_t)(ibase + ii + 1) * 64;
            for (int t = tid; t < 896; t += 256) {
                int c = t >> 3, seg = t & 7;
                *(short8*)&sW[buf ^ 1][c * 72 + seg * 8] =
                    *(const short8*)&WT[(size_t)c * cK + ksrc + seg * 8];
            }
        }
        const ushort* sWb = sW[buf];
        float h0 = bf2f(sH[(wbase + col) * 40 + ii]);
        float h1 = bf2f(sH[(wbase + 16 + col) * 40 + ii]);
#pragma unroll
        for (int j0 = 0; j0 < 64; j0 += 32) {
            short8 t0 = *(const short8*)&sT[(wbase + col) * 72 + j0 + g * 8];
            short8 t1 = *(const short8*)&sT[(wbase + 16 + col) * 72 + j0 + g * 8];
            short8 a0, a1;
#pragma unroll
            for (int jj = 0; jj < 8; jj++) {
                a0[jj] = (short)f2bf(h0 * bf2f((ushort)t0[jj]));
                a1[jj] = (short)f2bf(h1 * bf2f((ushort)t1[jj]));
            }
#pragma unroll
            for (int ct = 0; ct < 7; ct++) {
                short8 bfr = *(const short8*)&sWb[(ct * 16 + col) * 72 + j0 + g * 8];
                acc[0][ct] = __builtin_amdgcn_mfma_f32_16x16x32_bf16(a0, bfr, acc[0][ct], 0, 0, 0);
                acc[1][ct] = __builtin_amdgcn_mfma_f32_16x16x32_bf16(a1, bfr, acc[1][ct], 0, 0, 0);
            }
        }
        __syncthreads();
    }

#pragma unroll
    for (int mt = 0; mt < 2; mt++) {
#pragma unroll
        for (int ct = 0; ct < 7; ct++) {
            int c = ct * 16 + col;
            if (c < cC) {
                int rowb = n0 + wbase + mt * 16 + g * 4;
#pragma unroll
                for (int reg = 0; reg < 4; reg++)
                    atomicAdd(&out[(size_t)(rowb + reg) * cC + c], acc[mt][ct][reg]);
            }
        }
    }
}

// ---------------------------------------------------------------------------
extern "C" void kernel_launch(void* const* d_in, const int* in_sizes, int n_in,
                              void* d_out, int out_size, void* d_ws, size_t ws_size,
                              hipStream_t stream) {
    const float* seq_lhs  = (const float*)d_in[0];
    const float* ent_lhs  = (const float*)d_in[1];
    const float* attn     = (const float*)d_in[2];
    const int*   ids      = (const int*)d_in[3];
    const int*   hts      = (const int*)d_in[4];
    const float* head_W   = (const float*)d_in[5];
    const float* head_b   = (const float*)d_in[6];
    const float* tail_W   = (const float*)d_in[7];
    const float* tail_b   = (const float*)d_in[8];
    const float* bil_W    = (const float*)d_in[9];
    const float* bil_b    = (const float*)d_in[10];
    float* out = (float*)d_out;

    // workspace layout (byte offsets, all 16B-aligned)
    char* ws = (char*)d_ws;
    int*    counts   = (int*)(ws + 0);             // 512 B
    ushort* ent_bf   = (ushort*)(ws + 512);        // 131072 u16   -> 262144 B
    float*  ent_attn = (float*)(ws + 262656);      // 2097152 f    -> 8388608 B
    ushort* wbuf     = (ushort*)(ws + 8651264);    // 4063232 u16  -> 8126464 B
    ushort* relbf    = (ushort*)(ws + 16777728);   // 4063232 u16  -> 8126464 B
    ushort* hsp      = (ushort*)(ws + 24904192);   // 3047424 u16  -> 6094848 B
    ushort* tsp      = (ushort*)(ws + 30999040);   // 3047424 u16  -> 6094848 B
    ushort* WT       = (ushort*)(ws + 37093888);   // 112*49152    -> 11010048 B
    ushort* WTh      = (ushort*)(ws + 48103936);   // 768*2048     -> 3145728 B
    ushort* WTt      = (ushort*)(ws + 51249664);   // 768*2048     -> 3145728 B
    ushort* seqT     = (ushort*)(ws + 54395392);   // 4*1024*1024  -> 8388608 B

    // transposes / bf16 prep
    hipLaunchKernelGGL(tr_bf16_k, dim3(cK / 32, 4, 1), dim3(256), 0, stream,
                       bil_W, WT, cK, cC, 112);
    hipLaunchKernelGGL(tr_bf16_k, dim3(64, 24, 1), dim3(256), 0, stream,
                       head_W, WTh, 2 * cH, cEMB, cEMB);
    hipLaunchKernelGGL(tr_bf16_k, dim3(64, 24, 1), dim3(256), 0, stream,
                       tail_W, WTt, 2 * cH, cEMB, cEMB);
    hipLaunchKernelGGL(tr_bf16_k, dim3(32, 32, cB), dim3(256), 0, stream,
                       seq_lhs, seqT, cL, cH, cH);

    hipLaunchKernelGGL(ent_pool_k, dim3(cE, cB), dim3(256), 0, stream,
                       ent_lhs, ids, ent_bf, counts);
    hipLaunchKernelGGL(ent_attn_k, dim3(cB * cA, cL / 256), dim3(256), 0, stream,
                       attn, ids, counts, ent_attn);
    hipLaunchKernelGGL(w_k, dim3(cN), dim3(256), 0, stream,
                       ent_attn, hts, wbuf);
    hipLaunchKernelGGL(rel_mfma_k, dim3(8, 16, cB), dim3(256), 0, stream,
                       wbuf, seqT, relbf);
    hipLaunchKernelGGL(proj_mfma_k, dim3(cN / 128, cEMB / 64), dim3(256), 0, stream,
                       ent_bf, relbf, hts, WTh, head_b, hsp, 0);
    hipLaunchKernelGGL(proj_mfma_k, dim3(cN / 128, cEMB / 64), dim3(256), 0, stream,
                       ent_bf, relbf, hts, WTt, tail_b, tsp, 1);
    hipLaunchKernelGGL(out_init_k, dim3((cN * cC + 255) / 256), dim3(256), 0, stream,
                       bil_b, out);
    hipLaunchKernelGGL(bil_mfma_k, dim3(cN / 128, 24), dim3(256), 0, stream,
                       hsp, tsp, WT, out);
}

// Round 4
// 511.137 us; speedup vs baseline: 4.9827x; 1.1246x over previous
//
#include <hip/hip_runtime.h>
#include <hip/hip_bf16.h>
#include <math.h>

// Problem constants
constexpr int cB   = 4;
constexpr int cL   = 1024;
constexpr int cH   = 1024;
constexpr int cA   = 16;
constexpr int cM   = 128;
constexpr int cE   = 32;
constexpr int cR   = 992;
constexpr int cEMB = 768;
constexpr int cC   = 97;
constexpr int cN   = cB * cR;   // 3968

typedef unsigned short ushort;
typedef __attribute__((ext_vector_type(8))) short short8;
typedef __attribute__((ext_vector_type(4))) float float4v;

static __device__ inline float bf2f(ushort u) {
    unsigned v = ((unsigned)u) << 16;
    float f;
    __builtin_memcpy(&f, &v, 4);
    return f;
}
static __device__ inline ushort f2bf(float f) {
    unsigned u;
    __builtin_memcpy(&u, &f, 4);
    unsigned r = (u + 0x7FFFu + ((u >> 16) & 1u)) >> 16;
    return (ushort)r;
}

// true-async global->LDS, 16B per lane (HW: wave-uniform base + lane*16)
static __device__ inline void gld_lds16(void* lds, const void* gsrc) {
    __builtin_amdgcn_global_load_lds(
        (const __attribute__((address_space(1))) unsigned int*)gsrc,
        (__attribute__((address_space(3))) unsigned int*)lds, 16, 0, 0);
}

// ---------------------------------------------------------------------------
// Generic transpose f32 -> bf16: src[z][R][C] -> dst[z][Cp][R], zero-pad c>=C
__global__ void tr_bf16_k(const float* __restrict__ src, ushort* __restrict__ dst,
                          int R, int C, int Cp) {
    int z = blockIdx.z;
    int r0 = blockIdx.x * 32, c0 = blockIdx.y * 32;
    int tx = threadIdx.x & 31, ty = threadIdx.x >> 5;  // ty 0..7
    __shared__ float tile[32][33];
    for (int p = 0; p < 4; p++) {
        int r = r0 + ty + p * 8, c = c0 + tx;
        tile[ty + p * 8][tx] = (r < R && c < C) ? src[((size_t)z * R + r) * C + c] : 0.f;
    }
    __syncthreads();
    for (int p = 0; p < 4; p++) {
        int c = c0 + ty + p * 8, r = r0 + tx;
        if (c < Cp && r < R)
            dst[((size_t)z * Cp + c) * R + r] = f2bf(tile[tx][ty + p * 8]);
    }
}

// ---------------------------------------------------------------------------
// Build fragment-ordered bilinear weights:
// Wf[si][f][lane][8] bf16,  si = 0..767 (global i index), f = khalf*8+ct (16 frags),
// element = W[(si*64 + j)][c], j = khalf*32 + (lane>>4)*8 + jj, c = (ct*16 + lane&15),
// zero for c >= 97.  One block per si.
__global__ void wf_build_k(const float* __restrict__ W, ushort* __restrict__ Wf) {
    const int si = blockIdx.x;
    const int tid = threadIdx.x;
    __shared__ ushort sWb[64 * 136];
    for (int idx = tid; idx < 64 * 128; idx += 256) {
        int r = idx >> 7, c = idx & 127;
        float v = (c < cC) ? W[((size_t)si * 64 + r) * cC + c] : 0.f;
        sWb[r * 136 + c] = f2bf(v);
    }
    __syncthreads();
#pragma unroll
    for (int p = 0; p < 4; p++) {
        int e = tid + p * 256;          // 0..1023
        int f = e >> 6, lane = e & 63;
        int g = lane >> 4, col = lane & 15;
        int khalf = f >> 3, ct = f & 7;
        int jb = khalf * 32 + g * 8;
        int c = ct * 16 + col;
        short8 v;
#pragma unroll
        for (int jj = 0; jj < 8; jj++) v[jj] = (short)sWb[(jb + jj) * 136 + c];
        *(short8*)&Wf[(((size_t)si * 16 + f) * 64 + lane) * 8] = v;
    }
}

// ---------------------------------------------------------------------------
// Kernel 1: per-(b,e) logsumexp pooling of ent_lhs; writes bf16
__global__ void ent_pool_k(const float* __restrict__ ent_lhs, const int* __restrict__ ids,
                           ushort* __restrict__ ent_emb, int* __restrict__ counts) {
    int e = blockIdx.x, b = blockIdx.y;
    __shared__ int sid[cM];
    int tid = threadIdx.x;
    if (tid < cM) sid[tid] = ids[b * cM + tid];
    __syncthreads();
    int cnt = 0;
    for (int m = 0; m < cM; m++) cnt += (sid[m] == e) ? 1 : 0;
    if (tid == 0) counts[b * cE + e] = cnt;
    for (int h = tid; h < cH; h += 256) {
        float mx = -1e30f;
        for (int m = 0; m < cM; m++)
            if (sid[m] == e) mx = fmaxf(mx, ent_lhs[(size_t)(b * cM + m) * cH + h]);
        float s = 0.f;
        for (int m = 0; m < cM; m++)
            if (sid[m] == e) s += __expf(ent_lhs[(size_t)(b * cM + m) * cH + h] - mx);
        ent_emb[(size_t)(b * cE + e) * cH + h] = f2bf((cnt > 0) ? (mx + __logf(s)) : 0.f);
    }
}

// ---------------------------------------------------------------------------
// Kernel 2: ent_attn[b][e][a][l] (bf16 now) = segment-mean of attn
__global__ void ent_attn_k(const float* __restrict__ attn, const int* __restrict__ ids,
                           const int* __restrict__ counts, ushort* __restrict__ ent_attn) {
    int ba = blockIdx.x;
    int b = ba / cA, a = ba % cA;
    int tid = threadIdx.x;
    int l = blockIdx.y * 256 + tid;
    __shared__ int sid[cM];
    __shared__ int scnt[cE];
    __shared__ float sacc[256 * 33];
    if (tid < cM) sid[tid] = ids[b * cM + tid];
    if (tid < cE) scnt[tid] = counts[b * cE + tid];
    float* acc = &sacc[tid * 33];
    for (int e2 = 0; e2 < cE; e2++) acc[e2] = 0.f;
    __syncthreads();
    const float* ap = attn + ((size_t)(b * cA + a) * cM) * cL + l;
    for (int m = 0; m < cM; m++) acc[sid[m]] += ap[(size_t)m * cL];
    for (int e2 = 0; e2 < cE; e2++) {
        ent_attn[((size_t)(b * cE + e2) * cA + a) * cL + l] =
            f2bf(acc[e2] / (float)max(scnt[e2], 1));
    }
}

// ---------------------------------------------------------------------------
// Kernel 3: w[b][r][l] = mean_a ha*ta, normalized over l; bf16 in, bf16 out
__global__ void w_k(const ushort* __restrict__ ent_attn, const int* __restrict__ hts,
                    ushort* __restrict__ w) {
    int nr = blockIdx.x;
    int b = nr / cR;
    int he = hts[nr * 2 + 0], te = hts[nr * 2 + 1];
    int tid = threadIdx.x;
    const ushort* ha = ent_attn + ((size_t)(b * cE + he) * cA) * cL;
    const ushort* ta = ent_attn + ((size_t)(b * cE + te) * cA) * cL;
    float v[4];
    float psum = 0.f;
    for (int i = 0; i < 4; i++) {
        int l = tid + i * 256;
        float s = 0.f;
        for (int a = 0; a < cA; a++)
            s += bf2f(ha[(size_t)a * cL + l]) * bf2f(ta[(size_t)a * cL + l]);
        s *= (1.0f / cA);
        v[i] = s;
        psum += s;
    }
    for (int off = 32; off > 0; off >>= 1) psum += __shfl_down(psum, off, 64);
    __shared__ float red[4];
    if ((tid & 63) == 0) red[tid >> 6] = psum;
    __syncthreads();
    float tot = red[0] + red[1] + red[2] + red[3];
    float inv = 1.0f / (tot + 1e-5f);
    for (int i = 0; i < 4; i++) w[(size_t)nr * cL + tid + i * 256] = f2bf(v[i] * inv);
}

// ---------------------------------------------------------------------------
// Kernel 4: rel MFMA GEMM: rel[n][h] = sum_l w[n][l] * seqT[b][h][l]
__global__ __launch_bounds__(256) void
rel_mfma_k(const ushort* __restrict__ wbf, const ushort* __restrict__ seqT,
           ushort* __restrict__ relbf) {
    const int b = blockIdx.z;
    const int r0 = blockIdx.x * 128, h0 = blockIdx.y * 64;
    const int tid = threadIdx.x, lane = tid & 63, wv = tid >> 6;
    const int col = lane & 15, g = lane >> 4;

    __shared__ ushort sA[128 * 72];
    __shared__ ushort sB[64 * 72];

    float4v acc[2][4];
#pragma unroll
    for (int mt = 0; mt < 2; mt++)
#pragma unroll
        for (int ct = 0; ct < 4; ct++) acc[mt][ct] = (float4v){0.f, 0.f, 0.f, 0.f};

    for (int kt = 0; kt < cL; kt += 64) {
#pragma unroll
        for (int p = 0; p < 4; p++) {
            int t = tid + p * 256;
            int row = t >> 3, seg = t & 7;
            int r = min(r0 + row, cR - 1);
            *(short8*)&sA[row * 72 + seg * 8] =
                *(const short8*)&wbf[((size_t)b * cR + r) * cL + kt + seg * 8];
        }
#pragma unroll
        for (int p = 0; p < 2; p++) {
            int t = tid + p * 256;
            int c = t >> 3, seg = t & 7;
            *(short8*)&sB[c * 72 + seg * 8] =
                *(const short8*)&seqT[((size_t)b * cH + h0 + c) * cL + kt + seg * 8];
        }
        __syncthreads();
        const int wrow = wv * 32;
#pragma unroll
        for (int k0 = 0; k0 < 64; k0 += 32) {
            short8 a0 = *(const short8*)&sA[(wrow + col) * 72 + k0 + g * 8];
            short8 a1 = *(const short8*)&sA[(wrow + 16 + col) * 72 + k0 + g * 8];
#pragma unroll
            for (int ct = 0; ct < 4; ct++) {
                short8 bf = *(const short8*)&sB[(ct * 16 + col) * 72 + k0 + g * 8];
                acc[0][ct] = __builtin_amdgcn_mfma_f32_16x16x32_bf16(a0, bf, acc[0][ct], 0, 0, 0);
                acc[1][ct] = __builtin_amdgcn_mfma_f32_16x16x32_bf16(a1, bf, acc[1][ct], 0, 0, 0);
            }
        }
        __syncthreads();
    }
#pragma unroll
    for (int mt = 0; mt < 2; mt++) {
#pragma unroll
        for (int ct = 0; ct < 4; ct++) {
            int h = h0 + ct * 16 + col;
            int rowb = r0 + wv * 32 + mt * 16 + g * 4;
#pragma unroll
            for (int reg = 0; reg < 4; reg++) {
                int r = rowb + reg;
                if (r < cR)
                    relbf[((size_t)b * cR + r) * cH + h] = f2bf(acc[mt][ct][reg]);
            }
        }
    }
}

// ---------------------------------------------------------------------------
// Kernel 5: projection MFMA GEMM with gathered A
__global__ __launch_bounds__(256) void
proj_mfma_k(const ushort* __restrict__ ent_bf, const ushort* __restrict__ relbf,
            const int* __restrict__ hts, const ushort* __restrict__ WTp,
            const float* __restrict__ bias, ushort* __restrict__ outp, int sel) {
    const int n0 = blockIdx.x * 128, e0 = blockIdx.y * 64;
    const int tid = threadIdx.x, lane = tid & 63, wv = tid >> 6;
    const int col = lane & 15, g = lane >> 4;

    __shared__ int sbase[128];
    __shared__ ushort sA[128 * 72];
    __shared__ ushort sB[64 * 72];

    if (tid < 128) {
        int n = n0 + tid, bb = n / cR;
        sbase[tid] = (bb * cE + hts[n * 2 + sel]) * cH;
    }
    __syncthreads();

    float4v acc[2][4];
#pragma unroll
    for (int mt = 0; mt < 2; mt++)
#pragma unroll
        for (int ct = 0; ct < 4; ct++) acc[mt][ct] = (float4v){0.f, 0.f, 0.f, 0.f};

    for (int kt = 0; kt < 2 * cH; kt += 64) {
        const bool first = kt < cH;
#pragma unroll
        for (int p = 0; p < 4; p++) {
            int t = tid + p * 256;
            int row = t >> 3, seg = t & 7;
            const ushort* src = first
                ? &ent_bf[(size_t)sbase[row] + kt + seg * 8]
                : &relbf[(size_t)(n0 + row) * cH + (kt - cH) + seg * 8];
            *(short8*)&sA[row * 72 + seg * 8] = *(const short8*)src;
        }
#pragma unroll
        for (int p = 0; p < 2; p++) {
            int t = tid + p * 256;
            int c = t >> 3, seg = t & 7;
            *(short8*)&sB[c * 72 + seg * 8] =
                *(const short8*)&WTp[(size_t)(e0 + c) * (2 * cH) + kt + seg * 8];
        }
        __syncthreads();
        const int wrow = wv * 32;
#pragma unroll
        for (int k0 = 0; k0 < 64; k0 += 32) {
            short8 a0 = *(const short8*)&sA[(wrow + col) * 72 + k0 + g * 8];
            short8 a1 = *(const short8*)&sA[(wrow + 16 + col) * 72 + k0 + g * 8];
#pragma unroll
            for (int ct = 0; ct < 4; ct++) {
                short8 bf = *(const short8*)&sB[(ct * 16 + col) * 72 + k0 + g * 8];
                acc[0][ct] = __builtin_amdgcn_mfma_f32_16x16x32_bf16(a0, bf, acc[0][ct], 0, 0, 0);
                acc[1][ct] = __builtin_amdgcn_mfma_f32_16x16x32_bf16(a1, bf, acc[1][ct], 0, 0, 0);
            }
        }
        __syncthreads();
    }
#pragma unroll
    for (int mt = 0; mt < 2; mt++) {
#pragma unroll
        for (int ct = 0; ct < 4; ct++) {
            int e = e0 + ct * 16 + col;
            float bv = bias[e];
            int rowb = n0 + wv * 32 + mt * 16 + g * 4;
#pragma unroll
            for (int reg = 0; reg < 4; reg++)
                outp[(size_t)(rowb + reg) * cEMB + e] = f2bf(tanhf(acc[mt][ct][reg] + bv));
        }
    }
}

// ---------------------------------------------------------------------------
// Kernel 6a: out init with bias
__global__ void out_init_k(const float* __restrict__ bil_b, float* __restrict__ out) {
    int idx = blockIdx.x * 256 + threadIdx.x;
    if (idx < cN * cC) out[idx] = bil_b[idx % cC];
}

// ---------------------------------------------------------------------------
// Kernel 6b: bilinear v2.
// out[n][c] += sum_{i in slice} hs[n][i] * ( sum_j ts[n][j] * W[i*64+j][c] )
// A-operand = ts (registers, loaded once). B-operand = Wf fragments, staged
// async (global_load_lds w=16, double-buffered). hs-scale applied post-MFMA
// in f32 from LDS. Waves: 2x2 split (row-half x col-half), 128 rows x 128 cols
// (cols 97..127 are zero pad). grid (31, 24).
__global__ __launch_bounds__(256, 3) void
bil_mfma2_k(const ushort* __restrict__ hsp, const ushort* __restrict__ tsp,
            const ushort* __restrict__ Wf, float* __restrict__ out) {
    const int n0 = blockIdx.x * 128;
    const int islice = blockIdx.y;       // 0..23 (32 i's each)
    const int kb = islice >> 1;          // ts column block
    const int tid = threadIdx.x;
    const int lane = tid & 63, wv = tid >> 6;
    const int col = lane & 15, g = lane >> 4;
    const int rh = wv >> 1, cth = wv & 1;

    __shared__ ushort sW[2][8192];       // 16 frags x 64 lanes x 8 shorts
    __shared__ float sHs[32 * 132];      // [i][row], stride 132 (16B-aligned)

    // stage hs tile -> f32 LDS, transposed [i][row]
    for (int idx = tid; idx < 512; idx += 256) {
        int row = idx & 127, seg = idx >> 7;  // seg 0..3, 8 i's each
        short8 v = *(const short8*)&hsp[(size_t)(n0 + row) * cEMB + islice * 32 + seg * 8];
#pragma unroll
        for (int jj = 0; jj < 8; jj++)
            sHs[(seg * 8 + jj) * 132 + row] = bf2f((ushort)v[jj]);
    }

    // ts A-fragments: rows rh*64 + mt*16 + col, k = kh*32 + g*8 + jj
    short8 tsA[4][2];
#pragma unroll
    for (int mt = 0; mt < 4; mt++)
#pragma unroll
        for (int kh = 0; kh < 2; kh++)
            tsA[mt][kh] = *(const short8*)
                &tsp[(size_t)(n0 + rh * 64 + mt * 16 + col) * cEMB + kb * 64 + kh * 32 + g * 8];

    float4v acc[4][4];
#pragma unroll
    for (int mt = 0; mt < 4; mt++)
#pragma unroll
        for (int ct = 0; ct < 4; ct++) acc[mt][ct] = (float4v){0.f, 0.f, 0.f, 0.f};

    const ushort* WfS = Wf + (size_t)islice * 32 * 8192;

    // prologue: async-stage i=0 into buf 0
#pragma unroll
    for (int p = 0; p < 4; p++)
        gld_lds16(&sW[0][p * 2048 + tid * 8], &WfS[p * 2048 + tid * 8]);

    for (int i = 0; i < 32; i++) {
        const int buf = i & 1;
        __syncthreads();  // drains async stage(i); all reads of buf^1 done
        if (i + 1 < 32) {
            const ushort* gsrc = &WfS[(size_t)(i + 1) * 8192];
#pragma unroll
            for (int p = 0; p < 4; p++)
                gld_lds16(&sW[buf ^ 1][p * 2048 + tid * 8], &gsrc[p * 2048 + tid * 8]);
        }
        // hs scale vectors for this i (broadcast reads)
        float4v hsv[4];
#pragma unroll
        for (int mt = 0; mt < 4; mt++)
            hsv[mt] = *(const float4v*)&sHs[i * 132 + rh * 64 + mt * 16 + g * 4];
#pragma unroll
        for (int ctl = 0; ctl < 4; ctl++) {
            int f0 = cth * 4 + ctl;
            short8 b0 = *(const short8*)&sW[buf][f0 * 512 + lane * 8];
            short8 b1 = *(const short8*)&sW[buf][(8 + f0) * 512 + lane * 8];
#pragma unroll
            for (int mt = 0; mt < 4; mt++) {
                float4v P = (float4v){0.f, 0.f, 0.f, 0.f};
                P = __builtin_amdgcn_mfma_f32_16x16x32_bf16(tsA[mt][0], b0, P, 0, 0, 0);
                P = __builtin_amdgcn_mfma_f32_16x16x32_bf16(tsA[mt][1], b1, P, 0, 0, 0);
                acc[mt][ctl] += hsv[mt] * P;
            }
        }
    }

    // epilogue: atomic combine over 24 slices
#pragma unroll
    for (int mt = 0; mt < 4; mt++) {
#pragma unroll
        for (int ctl = 0; ctl < 4; ctl++) {
            int c = (cth * 4 + ctl) * 16 + col;
            if (c < cC) {
                int rowb = n0 + rh * 64 + mt * 16 + g * 4;
#pragma unroll
                for (int reg = 0; reg < 4; reg++)
                    atomicAdd(&out[(size_t)(rowb + reg) * cC + c], acc[mt][ctl][reg]);
            }
        }
    }
}

// ---------------------------------------------------------------------------
extern "C" void kernel_launch(void* const* d_in, const int* in_sizes, int n_in,
                              void* d_out, int out_size, void* d_ws, size_t ws_size,
                              hipStream_t stream) {
    const float* seq_lhs  = (const float*)d_in[0];
    const float* ent_lhs  = (const float*)d_in[1];
    const float* attn     = (const float*)d_in[2];
    const int*   ids      = (const int*)d_in[3];
    const int*   hts      = (const int*)d_in[4];
    const float* head_W   = (const float*)d_in[5];
    const float* head_b   = (const float*)d_in[6];
    const float* tail_W   = (const float*)d_in[7];
    const float* tail_b   = (const float*)d_in[8];
    const float* bil_W    = (const float*)d_in[9];
    const float* bil_b    = (const float*)d_in[10];
    float* out = (float*)d_out;

    // workspace layout (byte offsets, 256B-aligned)
    char* ws = (char*)d_ws;
    int*    counts   = (int*)(ws + 0);             // 512 B
    ushort* ent_bf   = (ushort*)(ws + 512);        // 262144 B
    ushort* ent_attn = (ushort*)(ws + 262656);     // bf16, 4194304 B
    ushort* wbuf     = (ushort*)(ws + 4456960);    // 8126464 B
    ushort* relbf    = (ushort*)(ws + 12583424);   // 8126464 B
    ushort* hsp      = (ushort*)(ws + 20709888);   // 6094848 B
    ushort* tsp      = (ushort*)(ws + 26804736);   // 6094848 B
    ushort* Wf       = (ushort*)(ws + 32899584);   // 12582912 B
    ushort* WTh      = (ushort*)(ws + 45482496);   // 3145728 B
    ushort* WTt      = (ushort*)(ws + 48628224);   // 3145728 B
    ushort* seqT     = (ushort*)(ws + 51773952);   // 8388608 B  (end 60162560)

    hipLaunchKernelGGL(wf_build_k, dim3(768), dim3(256), 0, stream, bil_W, Wf);
    hipLaunchKernelGGL(tr_bf16_k, dim3(64, 24, 1), dim3(256), 0, stream,
                       head_W, WTh, 2 * cH, cEMB, cEMB);
    hipLaunchKernelGGL(tr_bf16_k, dim3(64, 24, 1), dim3(256), 0, stream,
                       tail_W, WTt, 2 * cH, cEMB, cEMB);
    hipLaunchKernelGGL(tr_bf16_k, dim3(32, 32, cB), dim3(256), 0, stream,
                       seq_lhs, seqT, cL, cH, cH);

    hipLaunchKernelGGL(ent_pool_k, dim3(cE, cB), dim3(256), 0, stream,
                       ent_lhs, ids, ent_bf, counts);
    hipLaunchKernelGGL(ent_attn_k, dim3(cB * cA, cL / 256), dim3(256), 0, stream,
                       attn, ids, counts, ent_attn);
    hipLaunchKernelGGL(w_k, dim3(cN), dim3(256), 0, stream,
                       ent_attn, hts, wbuf);
    hipLaunchKernelGGL(rel_mfma_k, dim3(8, 16, cB), dim3(256), 0, stream,
                       wbuf, seqT, relbf);
    hipLaunchKernelGGL(proj_mfma_k, dim3(cN / 128, cEMB / 64), dim3(256), 0, stream,
                       ent_bf, relbf, hts, WTh, head_b, hsp, 0);
    hipLaunchKernelGGL(proj_mfma_k, dim3(cN / 128, cEMB / 64), dim3(256), 0, stream,
                       ent_bf, relbf, hts, WTt, tail_b, tsp, 1);
    hipLaunchKernelGGL(out_init_k, dim3((cN * cC + 255) / 256), dim3(256), 0, stream,
                       bil_b, out);
    hipLaunchKernelGGL(bil_mfma2_k, dim3(cN / 128, 24), dim3(256), 0, stream,
                       hsp, tsp, Wf, out);
}

// Round 5
// 493.560 us; speedup vs baseline: 5.1601x; 1.0356x over previous
//
#include <hip/hip_runtime.h>
#include <hip/hip_bf16.h>
#include <math.h>

// Problem constants
constexpr int cB   = 4;
constexpr int cL   = 1024;
constexpr int cH   = 1024;
constexpr int cA   = 16;
constexpr int cM   = 128;
constexpr int cE   = 32;
constexpr int cR   = 992;
constexpr int cEMB = 768;
constexpr int cC   = 97;
constexpr int cN   = cB * cR;   // 3968

typedef unsigned short ushort;
typedef __attribute__((ext_vector_type(8))) short short8;
typedef __attribute__((ext_vector_type(4))) float float4v;

static __device__ inline float bf2f(ushort u) {
    unsigned v = ((unsigned)u) << 16;
    float f;
    __builtin_memcpy(&f, &v, 4);
    return f;
}
static __device__ inline ushort f2bf(float f) {
    unsigned u;
    __builtin_memcpy(&u, &f, 4);
    unsigned r = (u + 0x7FFFu + ((u >> 16) & 1u)) >> 16;
    return (ushort)r;
}

// ---------------------------------------------------------------------------
// Generic transpose f32 -> bf16: src[z][R][C] -> dst[z][Cp][R], zero-pad c>=C
__global__ void tr_bf16_k(const float* __restrict__ src, ushort* __restrict__ dst,
                          int R, int C, int Cp) {
    int z = blockIdx.z;
    int r0 = blockIdx.x * 32, c0 = blockIdx.y * 32;
    int tx = threadIdx.x & 31, ty = threadIdx.x >> 5;  // ty 0..7
    __shared__ float tile[32][33];
    for (int p = 0; p < 4; p++) {
        int r = r0 + ty + p * 8, c = c0 + tx;
        tile[ty + p * 8][tx] = (r < R && c < C) ? src[((size_t)z * R + r) * C + c] : 0.f;
    }
    __syncthreads();
    for (int p = 0; p < 4; p++) {
        int c = c0 + ty + p * 8, r = r0 + tx;
        if (c < Cp && r < R)
            dst[((size_t)z * Cp + c) * R + r] = f2bf(tile[tx][ty + p * 8]);
    }
}

// ---------------------------------------------------------------------------
// Build fragment-ordered bilinear weights:
// Wf[si][f][lane][8] bf16,  si = 0..767, f = khalf*8+ct,
// element = W[(si*64 + j)][c], j = khalf*32 + (lane>>4)*8 + jj, c = ct*16 + (lane&15),
// zero for c >= 97.  One block per si.
__global__ void wf_build_k(const float* __restrict__ W, ushort* __restrict__ Wf) {
    const int si = blockIdx.x;
    const int tid = threadIdx.x;
    __shared__ ushort sWb[64 * 136];
    for (int idx = tid; idx < 64 * 128; idx += 256) {
        int r = idx >> 7, c = idx & 127;
        float v = (c < cC) ? W[((size_t)si * 64 + r) * cC + c] : 0.f;
        sWb[r * 136 + c] = f2bf(v);
    }
    __syncthreads();
#pragma unroll
    for (int p = 0; p < 4; p++) {
        int e = tid + p * 256;          // 0..1023
        int f = e >> 6, lane = e & 63;
        int g = lane >> 4, col = lane & 15;
        int khalf = f >> 3, ct = f & 7;
        int jb = khalf * 32 + g * 8;
        int c = ct * 16 + col;
        short8 v;
#pragma unroll
        for (int jj = 0; jj < 8; jj++) v[jj] = (short)sWb[(jb + jj) * 136 + c];
        *(short8*)&Wf[(((size_t)si * 16 + f) * 64 + lane) * 8] = v;
    }
}

// ---------------------------------------------------------------------------
// Kernel 1: per-(b,e) logsumexp pooling of ent_lhs; writes bf16
__global__ void ent_pool_k(const float* __restrict__ ent_lhs, const int* __restrict__ ids,
                           ushort* __restrict__ ent_emb, int* __restrict__ counts) {
    int e = blockIdx.x, b = blockIdx.y;
    __shared__ int sid[cM];
    int tid = threadIdx.x;
    if (tid < cM) sid[tid] = ids[b * cM + tid];
    __syncthreads();
    int cnt = 0;
    for (int m = 0; m < cM; m++) cnt += (sid[m] == e) ? 1 : 0;
    if (tid == 0) counts[b * cE + e] = cnt;
    for (int h = tid; h < cH; h += 256) {
        float mx = -1e30f;
        for (int m = 0; m < cM; m++)
            if (sid[m] == e) mx = fmaxf(mx, ent_lhs[(size_t)(b * cM + m) * cH + h]);
        float s = 0.f;
        for (int m = 0; m < cM; m++)
            if (sid[m] == e) s += __expf(ent_lhs[(size_t)(b * cM + m) * cH + h] - mx);
        ent_emb[(size_t)(b * cE + e) * cH + h] = f2bf((cnt > 0) ? (mx + __logf(s)) : 0.f);
    }
}

// ---------------------------------------------------------------------------
// Kernel 2: ent_attn[b][e][a][l] (bf16) = segment-mean of attn
__global__ void ent_attn_k(const float* __restrict__ attn, const int* __restrict__ ids,
                           const int* __restrict__ counts, ushort* __restrict__ ent_attn) {
    int ba = blockIdx.x;
    int b = ba / cA, a = ba % cA;
    int tid = threadIdx.x;
    int l = blockIdx.y * 256 + tid;
    __shared__ int sid[cM];
    __shared__ int scnt[cE];
    __shared__ float sacc[256 * 33];
    if (tid < cM) sid[tid] = ids[b * cM + tid];
    if (tid < cE) scnt[tid] = counts[b * cE + tid];
    float* acc = &sacc[tid * 33];
    for (int e2 = 0; e2 < cE; e2++) acc[e2] = 0.f;
    __syncthreads();
    const float* ap = attn + ((size_t)(b * cA + a) * cM) * cL + l;
    for (int m = 0; m < cM; m++) acc[sid[m]] += ap[(size_t)m * cL];
    for (int e2 = 0; e2 < cE; e2++) {
        ent_attn[((size_t)(b * cE + e2) * cA + a) * cL + l] =
            f2bf(acc[e2] / (float)max(scnt[e2], 1));
    }
}

// ---------------------------------------------------------------------------
// Kernel 3: w[b][r][l] = mean_a ha*ta, normalized over l; bf16 in, bf16 out
__global__ void w_k(const ushort* __restrict__ ent_attn, const int* __restrict__ hts,
                    ushort* __restrict__ w) {
    int nr = blockIdx.x;
    int b = nr / cR;
    int he = hts[nr * 2 + 0], te = hts[nr * 2 + 1];
    int tid = threadIdx.x;
    const ushort* ha = ent_attn + ((size_t)(b * cE + he) * cA) * cL;
    const ushort* ta = ent_attn + ((size_t)(b * cE + te) * cA) * cL;
    float v[4];
    float psum = 0.f;
    for (int i = 0; i < 4; i++) {
        int l = tid + i * 256;
        float s = 0.f;
        for (int a = 0; a < cA; a++)
            s += bf2f(ha[(size_t)a * cL + l]) * bf2f(ta[(size_t)a * cL + l]);
        s *= (1.0f / cA);
        v[i] = s;
        psum += s;
    }
    for (int off = 32; off > 0; off >>= 1) psum += __shfl_down(psum, off, 64);
    __shared__ float red[4];
    if ((tid & 63) == 0) red[tid >> 6] = psum;
    __syncthreads();
    float tot = red[0] + red[1] + red[2] + red[3];
    float inv = 1.0f / (tot + 1e-5f);
    for (int i = 0; i < 4; i++) w[(size_t)nr * cL + tid + i * 256] = f2bf(v[i] * inv);
}

// ---------------------------------------------------------------------------
// Kernel 4: rel MFMA GEMM: rel[n][h] = sum_l w[n][l] * seqT[b][h][l]
__global__ __launch_bounds__(256) void
rel_mfma_k(const ushort* __restrict__ wbf, const ushort* __restrict__ seqT,
           ushort* __restrict__ relbf) {
    const int b = blockIdx.z;
    const int r0 = blockIdx.x * 128, h0 = blockIdx.y * 64;
    const int tid = threadIdx.x, lane = tid & 63, wv = tid >> 6;
    const int col = lane & 15, g = lane >> 4;

    __shared__ ushort sA[128 * 72];
    __shared__ ushort sB[64 * 72];

    float4v acc[2][4];
#pragma unroll
    for (int mt = 0; mt < 2; mt++)
#pragma unroll
        for (int ct = 0; ct < 4; ct++) acc[mt][ct] = (float4v){0.f, 0.f, 0.f, 0.f};

    for (int kt = 0; kt < cL; kt += 64) {
#pragma unroll
        for (int p = 0; p < 4; p++) {
            int t = tid + p * 256;
            int row = t >> 3, seg = t & 7;
            int r = min(r0 + row, cR - 1);
            *(short8*)&sA[row * 72 + seg * 8] =
                *(const short8*)&wbf[((size_t)b * cR + r) * cL + kt + seg * 8];
        }
#pragma unroll
        for (int p = 0; p < 2; p++) {
            int t = tid + p * 256;
            int c = t >> 3, seg = t & 7;
            *(short8*)&sB[c * 72 + seg * 8] =
                *(const short8*)&seqT[((size_t)b * cH + h0 + c) * cL + kt + seg * 8];
        }
        __syncthreads();
        const int wrow = wv * 32;
#pragma unroll
        for (int k0 = 0; k0 < 64; k0 += 32) {
            short8 a0 = *(const short8*)&sA[(wrow + col) * 72 + k0 + g * 8];
            short8 a1 = *(const short8*)&sA[(wrow + 16 + col) * 72 + k0 + g * 8];
#pragma unroll
            for (int ct = 0; ct < 4; ct++) {
                short8 bf = *(const short8*)&sB[(ct * 16 + col) * 72 + k0 + g * 8];
                acc[0][ct] = __builtin_amdgcn_mfma_f32_16x16x32_bf16(a0, bf, acc[0][ct], 0, 0, 0);
                acc[1][ct] = __builtin_amdgcn_mfma_f32_16x16x32_bf16(a1, bf, acc[1][ct], 0, 0, 0);
            }
        }
        __syncthreads();
    }
#pragma unroll
    for (int mt = 0; mt < 2; mt++) {
#pragma unroll
        for (int ct = 0; ct < 4; ct++) {
            int h = h0 + ct * 16 + col;
            int rowb = r0 + wv * 32 + mt * 16 + g * 4;
#pragma unroll
            for (int reg = 0; reg < 4; reg++) {
                int r = rowb + reg;
                if (r < cR)
                    relbf[((size_t)b * cR + r) * cH + h] = f2bf(acc[mt][ct][reg]);
            }
        }
    }
}

// ---------------------------------------------------------------------------
// Kernel 5: projection MFMA GEMM with gathered A
__global__ __launch_bounds__(256) void
proj_mfma_k(const ushort* __restrict__ ent_bf, const ushort* __restrict__ relbf,
            const int* __restrict__ hts, const ushort* __restrict__ WTp,
            const float* __restrict__ bias, ushort* __restrict__ outp, int sel) {
    const int n0 = blockIdx.x * 128, e0 = blockIdx.y * 64;
    const int tid = threadIdx.x, lane = tid & 63, wv = tid >> 6;
    const int col = lane & 15, g = lane >> 4;

    __shared__ int sbase[128];
    __shared__ ushort sA[128 * 72];
    __shared__ ushort sB[64 * 72];

    if (tid < 128) {
        int n = n0 + tid, bb = n / cR;
        sbase[tid] = (bb * cE + hts[n * 2 + sel]) * cH;
    }
    __syncthreads();

    float4v acc[2][4];
#pragma unroll
    for (int mt = 0; mt < 2; mt++)
#pragma unroll
        for (int ct = 0; ct < 4; ct++) acc[mt][ct] = (float4v){0.f, 0.f, 0.f, 0.f};

    for (int kt = 0; kt < 2 * cH; kt += 64) {
        const bool first = kt < cH;
#pragma unroll
        for (int p = 0; p < 4; p++) {
            int t = tid + p * 256;
            int row = t >> 3, seg = t & 7;
            const ushort* src = first
                ? &ent_bf[(size_t)sbase[row] + kt + seg * 8]
                : &relbf[(size_t)(n0 + row) * cH + (kt - cH) + seg * 8];
            *(short8*)&sA[row * 72 + seg * 8] = *(const short8*)src;
        }
#pragma unroll
        for (int p = 0; p < 2; p++) {
            int t = tid + p * 256;
            int c = t >> 3, seg = t & 7;
            *(short8*)&sB[c * 72 + seg * 8] =
                *(const short8*)&WTp[(size_t)(e0 + c) * (2 * cH) + kt + seg * 8];
        }
        __syncthreads();
        const int wrow = wv * 32;
#pragma unroll
        for (int k0 = 0; k0 < 64; k0 += 32) {
            short8 a0 = *(const short8*)&sA[(wrow + col) * 72 + k0 + g * 8];
            short8 a1 = *(const short8*)&sA[(wrow + 16 + col) * 72 + k0 + g * 8];
#pragma unroll
            for (int ct = 0; ct < 4; ct++) {
                short8 bf = *(const short8*)&sB[(ct * 16 + col) * 72 + k0 + g * 8];
                acc[0][ct] = __builtin_amdgcn_mfma_f32_16x16x32_bf16(a0, bf, acc[0][ct], 0, 0, 0);
                acc[1][ct] = __builtin_amdgcn_mfma_f32_16x16x32_bf16(a1, bf, acc[1][ct], 0, 0, 0);
            }
        }
        __syncthreads();
    }
#pragma unroll
    for (int mt = 0; mt < 2; mt++) {
#pragma unroll
        for (int ct = 0; ct < 4; ct++) {
            int e = e0 + ct * 16 + col;
            float bv = bias[e];
            int rowb = n0 + wv * 32 + mt * 16 + g * 4;
#pragma unroll
            for (int reg = 0; reg < 4; reg++)
                outp[(size_t)(rowb + reg) * cEMB + e] = f2bf(tanhf(acc[mt][ct][reg] + bv));
        }
    }
}

// ---------------------------------------------------------------------------
// Kernel 6a: out init with bias
__global__ void out_init_k(const float* __restrict__ bil_b, float* __restrict__ out) {
    int idx = blockIdx.x * 256 + threadIdx.x;
    if (idx < cN * cC) out[idx] = bil_b[idx % cC];
}

// ---------------------------------------------------------------------------
// Kernel 6b: bilinear v3 — barrier-free K-loop.
// out[n][c] += sum_i hs[n][i] * ( sum_j ts[n][j] * W[i*64+j][c] )
// ts in registers (A-operand), W fragments global->VGPR double-buffered
// (no LDS, no per-iter barrier; W frag reuse is only 2x so LDS bought little),
// hs transposed in LDS (one barrier total). grid (24 islices, 31 n-tiles):
// linear block id % 8 == islice % 8 -> each XCD sees 3 islices -> Wf working
// set 1.57 MB/XCD, L2-resident.
__global__ __launch_bounds__(256, 2) void
bil_mfma3_k(const ushort* __restrict__ hsp, const ushort* __restrict__ tsp,
            const ushort* __restrict__ Wf, float* __restrict__ out) {
    const int islice = blockIdx.x;       // 0..23
    const int n0 = blockIdx.y * 128;
    const int kb = islice >> 1;          // ts column block
    const int tid = threadIdx.x;
    const int lane = tid & 63, wv = tid >> 6;
    const int col = lane & 15, g = lane >> 4;
    const int rh = wv >> 1, cth = wv & 1;

    __shared__ float sHs[32 * 132];      // [i][row]

    // stage hs tile -> f32 LDS, transposed
    for (int idx = tid; idx < 512; idx += 256) {
        int row = idx & 127, seg = idx >> 7;
        short8 v = *(const short8*)&hsp[(size_t)(n0 + row) * cEMB + islice * 32 + seg * 8];
#pragma unroll
        for (int jj = 0; jj < 8; jj++)
            sHs[(seg * 8 + jj) * 132 + row] = bf2f((ushort)v[jj]);
    }

    // ts A-fragments (held in registers for all 32 iterations)
    short8 tsA[4][2];
#pragma unroll
    for (int mt = 0; mt < 4; mt++)
#pragma unroll
        for (int kh = 0; kh < 2; kh++)
            tsA[mt][kh] = *(const short8*)
                &tsp[(size_t)(n0 + rh * 64 + mt * 16 + col) * cEMB + kb * 64 + kh * 32 + g * 8];

    float4v acc[4][4];
#pragma unroll
    for (int mt = 0; mt < 4; mt++)
#pragma unroll
        for (int ct = 0; ct < 4; ct++) acc[mt][ct] = (float4v){0.f, 0.f, 0.f, 0.f};

    const ushort* WfS = Wf + (size_t)islice * 32 * 8192;

#define WFRAG(i, ctl, kh) \
    (*(const short8*)&WfS[(((size_t)(i) * 16 + (kh) * 8 + cth * 4 + (ctl)) * 64 + lane) * 8])

    short8 w0[8], w1[8];
#pragma unroll
    for (int ctl = 0; ctl < 4; ctl++) {
        w0[ctl * 2 + 0] = WFRAG(0, ctl, 0);
        w0[ctl * 2 + 1] = WFRAG(0, ctl, 1);
    }
    __syncthreads();  // hs staged (the only barrier)

    for (int i = 0; i < 32; i += 2) {
        // prefetch i+1 while computing i
#pragma unroll
        for (int ctl = 0; ctl < 4; ctl++) {
            w1[ctl * 2 + 0] = WFRAG(i + 1, ctl, 0);
            w1[ctl * 2 + 1] = WFRAG(i + 1, ctl, 1);
        }
        {
            float4v hsv[4];
#pragma unroll
            for (int mt = 0; mt < 4; mt++)
                hsv[mt] = *(const float4v*)&sHs[i * 132 + rh * 64 + mt * 16 + g * 4];
#pragma unroll
            for (int ctl = 0; ctl < 4; ctl++) {
#pragma unroll
                for (int mt = 0; mt < 4; mt++) {
                    float4v P = (float4v){0.f, 0.f, 0.f, 0.f};
                    P = __builtin_amdgcn_mfma_f32_16x16x32_bf16(tsA[mt][0], w0[ctl * 2 + 0], P, 0, 0, 0);
                    P = __builtin_amdgcn_mfma_f32_16x16x32_bf16(tsA[mt][1], w0[ctl * 2 + 1], P, 0, 0, 0);
                    acc[mt][ctl] += hsv[mt] * P;
                }
            }
        }
        // prefetch i+2 while computing i+1
        if (i + 2 < 32) {
#pragma unroll
            for (int ctl = 0; ctl < 4; ctl++) {
                w0[ctl * 2 + 0] = WFRAG(i + 2, ctl, 0);
                w0[ctl * 2 + 1] = WFRAG(i + 2, ctl, 1);
            }
        }
        {
            float4v hsv[4];
#pragma unroll
            for (int mt = 0; mt < 4; mt++)
                hsv[mt] = *(const float4v*)&sHs[(i + 1) * 132 + rh * 64 + mt * 16 + g * 4];
#pragma unroll
            for (int ctl = 0; ctl < 4; ctl++) {
#pragma unroll
                for (int mt = 0; mt < 4; mt++) {
                    float4v P = (float4v){0.f, 0.f, 0.f, 0.f};
                    P = __builtin_amdgcn_mfma_f32_16x16x32_bf16(tsA[mt][0], w1[ctl * 2 + 0], P, 0, 0, 0);
                    P = __builtin_amdgcn_mfma_f32_16x16x32_bf16(tsA[mt][1], w1[ctl * 2 + 1], P, 0, 0, 0);
                    acc[mt][ctl] += hsv[mt] * P;
                }
            }
        }
    }
#undef WFRAG

    // epilogue: atomic combine over 24 slices
#pragma unroll
    for (int mt = 0; mt < 4; mt++) {
#pragma unroll
        for (int ctl = 0; ctl < 4; ctl++) {
            int c = (cth * 4 + ctl) * 16 + col;
            if (c < cC) {
                int rowb = n0 + rh * 64 + mt * 16 + g * 4;
#pragma unroll
                for (int reg = 0; reg < 4; reg++)
                    atomicAdd(&out[(size_t)(rowb + reg) * cC + c], acc[mt][ctl][reg]);
            }
        }
    }
}

// ---------------------------------------------------------------------------
extern "C" void kernel_launch(void* const* d_in, const int* in_sizes, int n_in,
                              void* d_out, int out_size, void* d_ws, size_t ws_size,
                              hipStream_t stream) {
    const float* seq_lhs  = (const float*)d_in[0];
    const float* ent_lhs  = (const float*)d_in[1];
    const float* attn     = (const float*)d_in[2];
    const int*   ids      = (const int*)d_in[3];
    const int*   hts      = (const int*)d_in[4];
    const float* head_W   = (const float*)d_in[5];
    const float* head_b   = (const float*)d_in[6];
    const float* tail_W   = (const float*)d_in[7];
    const float* tail_b   = (const float*)d_in[8];
    const float* bil_W    = (const float*)d_in[9];
    const float* bil_b    = (const float*)d_in[10];
    float* out = (float*)d_out;

    // workspace layout (byte offsets, 256B-aligned)
    char* ws = (char*)d_ws;
    int*    counts   = (int*)(ws + 0);             // 512 B
    ushort* ent_bf   = (ushort*)(ws + 512);        // 262144 B
    ushort* ent_attn = (ushort*)(ws + 262656);     // bf16, 4194304 B
    ushort* wbuf     = (ushort*)(ws + 4456960);    // 8126464 B
    ushort* relbf    = (ushort*)(ws + 12583424);   // 8126464 B
    ushort* hsp      = (ushort*)(ws + 20709888);   // 6094848 B
    ushort* tsp      = (ushort*)(ws + 26804736);   // 6094848 B
    ushort* Wf       = (ushort*)(ws + 32899584);   // 12582912 B
    ushort* WTh      = (ushort*)(ws + 45482496);   // 3145728 B
    ushort* WTt      = (ushort*)(ws + 48628224);   // 3145728 B
    ushort* seqT     = (ushort*)(ws + 51773952);   // 8388608 B  (end 60162560)

    hipLaunchKernelGGL(wf_build_k, dim3(768), dim3(256), 0, stream, bil_W, Wf);
    hipLaunchKernelGGL(tr_bf16_k, dim3(64, 24, 1), dim3(256), 0, stream,
                       head_W, WTh, 2 * cH, cEMB, cEMB);
    hipLaunchKernelGGL(tr_bf16_k, dim3(64, 24, 1), dim3(256), 0, stream,
                       tail_W, WTt, 2 * cH, cEMB, cEMB);
    hipLaunchKernelGGL(tr_bf16_k, dim3(32, 32, cB), dim3(256), 0, stream,
                       seq_lhs, seqT, cL, cH, cH);

    hipLaunchKernelGGL(ent_pool_k, dim3(cE, cB), dim3(256), 0, stream,
                       ent_lhs, ids, ent_bf, counts);
    hipLaunchKernelGGL(ent_attn_k, dim3(cB * cA, cL / 256), dim3(256), 0, stream,
                       attn, ids, counts, ent_attn);
    hipLaunchKernelGGL(w_k, dim3(cN), dim3(256), 0, stream,
                       ent_attn, hts, wbuf);
    hipLaunchKernelGGL(rel_mfma_k, dim3(8, 16, cB), dim3(256), 0, stream,
                       wbuf, seqT, relbf);
    hipLaunchKernelGGL(proj_mfma_k, dim3(cN / 128, cEMB / 64), dim3(256), 0, stream,
                       ent_bf, relbf, hts, WTh, head_b, hsp, 0);
    hipLaunchKernelGGL(proj_mfma_k, dim3(cN / 128, cEMB / 64), dim3(256), 0, stream,
                       ent_bf, relbf, hts, WTt, tail_b, tsp, 1);
    hipLaunchKernelGGL(out_init_k, dim3((cN * cC + 255) / 256), dim3(256), 0, stream,
                       bil_b, out);
    hipLaunchKernelGGL(bil_mfma3_k, dim3(24, cN / 128), dim3(256), 0, stream,
                       hsp, tsp, Wf, out);
}